// Round 1
// baseline (1126.071 us; speedup 1.0000x reference)
//
#include <hip/hip_runtime.h>
#include <cmath>

#define DIMS 2048
#define SEQ  8192
#define NB   2
#define HEADS 16
#define HD   128
#define WINW 256
#define MROWS 16384  // NB*SEQ
#define NCH  32      // SEQ/WINW

using bf16x8 = __attribute__((ext_vector_type(8))) short;
using f32x4  = __attribute__((ext_vector_type(4))) float;

__device__ __forceinline__ unsigned short f2bf(float f) {
  unsigned int u = __float_as_uint(f);
  u += 0x7FFF + ((u >> 16) & 1);
  return (unsigned short)(u >> 16);
}

__device__ __forceinline__ void async16(const unsigned short* g, unsigned short* l) {
  __builtin_amdgcn_global_load_lds((const __attribute__((address_space(1))) void*)g,
                                   (__attribute__((address_space(3))) void*)l,
                                   16, 0, 0);
}

// ---------------- weight transpose+convert: W[K,N] f32 -> Wt[N,K] bf16 ----------------
__global__ void wconv(const float* __restrict__ w0, const float* __restrict__ w1,
                      const float* __restrict__ w2, const float* __restrict__ w3,
                      unsigned short* __restrict__ Wt) {
  __shared__ unsigned short tile[64][65];
  const float* W = (blockIdx.z == 0) ? w0 : (blockIdx.z == 1) ? w1 : (blockIdx.z == 2) ? w2 : w3;
  unsigned short* O = Wt + (size_t)blockIdx.z * DIMS * DIMS;
  const int k0 = blockIdx.y * 64, n0 = blockIdx.x * 64;
  const int t = threadIdx.x;
  #pragma unroll
  for (int p = 0; p < 16; ++p) {
    int i = p * 4 + (t >> 6);
    int j = t & 63;
    tile[i][j] = f2bf(W[(size_t)(k0 + i) * DIMS + n0 + j]);
  }
  __syncthreads();
  #pragma unroll
  for (int p = 0; p < 16; ++p) {
    int a = p * 4 + (t >> 6);
    int b = t & 63;
    O[(size_t)(n0 + a) * DIMS + k0 + b] = tile[b][a];
  }
}

// ---------------- hidden f32 -> bf16 ----------------
__global__ void hconv(const float* __restrict__ in, unsigned short* __restrict__ outp) {
  const long n4 = (long)MROWS * DIMS / 4;
  long i = (long)blockIdx.x * blockDim.x + threadIdx.x;
  const long stride = (long)gridDim.x * blockDim.x;
  for (; i < n4; i += stride) {
    float4 v = ((const float4*)in)[i];
    ushort4 o;
    o.x = f2bf(v.x); o.y = f2bf(v.y); o.z = f2bf(v.z); o.w = f2bf(v.w);
    ((ushort4*)outp)[i] = o;
  }
}

// ---------------- RoPE table: [8192][64] cos/sin ----------------
__global__ void rope_tab(float* __restrict__ cosT, float* __restrict__ sinT) {
  int t = blockIdx.x * 256 + threadIdx.x;  // 524288 total
  int pos = t >> 6, i = t & 63;
  double inv = pow(10000.0, -(double)i / 64.0);
  double ang = (double)pos * inv;
  cosT[t] = (float)cos(ang);
  sinT[t] = (float)sin(ang);
}

// ---------------- GEMM: A[M,K]bf16 @ Bt[N,K]^T, 128x128 tile, BK=64 ----------------
// MODE 0: QKV (bf16 out, rope when z<2).  MODE 1: O-proj (f32 out to d_out).
template<int MODE>
__global__ __launch_bounds__(256) void gemm_bt(
    const unsigned short* __restrict__ A,
    const unsigned short* __restrict__ WtAll,
    unsigned short* __restrict__ OutB,
    float* __restrict__ OutF,
    const float* __restrict__ cosT,
    const float* __restrict__ sinT) {
  __shared__ unsigned short Asm[128 * 64];
  __shared__ unsigned short Bsm[128 * 64];

  const int tid = threadIdx.x;
  const int wid = tid >> 6;
  const int lane = tid & 63;
  const int lo = lane & 15, hi = lane >> 4;
  const int m0 = blockIdx.y * 128;
  const int n0 = blockIdx.x * 128;
  const int z = blockIdx.z;
  const unsigned short* Bt = WtAll + (size_t)(MODE == 1 ? 3 : z) * DIMS * DIMS;

  f32x4 acc[2][8];
  #pragma unroll
  for (int m = 0; m < 2; ++m)
    #pragma unroll
    for (int n = 0; n < 8; ++n)
      acc[m][n] = (f32x4){0.f, 0.f, 0.f, 0.f};

  auto stage = [&](int kt) {
    const int k0 = kt * 64;
    #pragma unroll
    for (int it = 0; it < 4; ++it) {
      const int cid = it * 256 + tid;
      const int row = cid >> 3;
      const int k8 = (cid & 7) << 3;
      async16(A + (size_t)(m0 + row) * DIMS + k0 + k8,
              Asm + (size_t)(it * 256 + wid * 64) * 8);
    }
    #pragma unroll
    for (int it = 0; it < 4; ++it) {
      const int cid = it * 256 + tid;
      const int row = cid >> 3;
      const int k8 = (cid & 7) << 3;
      async16(Bt + (size_t)(n0 + row) * DIMS + k0 + k8,
              Bsm + (size_t)(it * 256 + wid * 64) * 8);
    }
  };

  stage(0);
  for (int kt = 0; kt < 32; ++kt) {
    __syncthreads();  // drains vmcnt: staged tile visible
    #pragma unroll
    for (int kk = 0; kk < 2; ++kk) {
      const int ko = kk * 32 + hi * 8;
      bf16x8 af[2], bfr[8];
      #pragma unroll
      for (int m = 0; m < 2; ++m)
        af[m] = *(const bf16x8*)&Asm[(wid * 32 + m * 16 + lo) * 64 + ko];
      #pragma unroll
      for (int n = 0; n < 8; ++n)
        bfr[n] = *(const bf16x8*)&Bsm[(n * 16 + lo) * 64 + ko];
      #pragma unroll
      for (int m = 0; m < 2; ++m)
        #pragma unroll
        for (int n = 0; n < 8; ++n)
          acc[m][n] = __builtin_amdgcn_mfma_f32_16x16x32_bf16(af[m], bfr[n], acc[m][n], 0, 0, 0);
    }
    __syncthreads();  // all waves done with LDS before restage
    if (kt < 31) stage(kt + 1);
  }

  // epilogue
  const int rope = (MODE == 0) && (z < 2);
  unsigned short* outb = (MODE == 0) ? (OutB + (size_t)z * MROWS * DIMS) : (unsigned short*)nullptr;
  #pragma unroll
  for (int m = 0; m < 2; ++m) {
    #pragma unroll
    for (int r = 0; r < 4; ++r) {
      const int row = m0 + wid * 32 + m * 16 + hi * 4 + r;
      const int s = row & (SEQ - 1);
      if (MODE == 1) {
        float* o = OutF + (size_t)row * DIMS + n0;
        #pragma unroll
        for (int n = 0; n < 8; ++n) o[n * 16 + lo] = acc[m][n][r];
      } else if (rope) {
        unsigned short* o = outb + (size_t)row * DIMS + n0;
        #pragma unroll
        for (int n = 0; n < 4; ++n) {
          const int d = n * 16 + lo;  // < 64; tile is head-aligned
          const float c = cosT[s * 64 + d], sn = sinT[s * 64 + d];
          const float v1 = acc[m][n][r], v2 = acc[m][n + 4][r];
          o[d]      = f2bf(v1 * c - v2 * sn);
          o[d + 64] = f2bf(v2 * c + v1 * sn);
        }
      } else {
        unsigned short* o = outb + (size_t)row * DIMS + n0;
        #pragma unroll
        for (int n = 0; n < 8; ++n) o[n * 16 + lo] = f2bf(acc[m][n][r]);
      }
    }
  }
}

// ---------------- block sliding-window attention ----------------
// grid: B*C*H = 1024 blocks; block = 512 threads = 8 waves; wave = 32 q-rows.
__global__ __launch_bounds__(512) void attn(
    const unsigned short* __restrict__ Qb,
    const unsigned short* __restrict__ Kb,
    const unsigned short* __restrict__ Vb,
    unsigned short* __restrict__ AO) {
  __shared__ unsigned short Ksm[64 * 136];      // [64 keys][128 d + 8 pad]
  __shared__ unsigned short Vsm[128 * 72];      // V^T: [128 d][64 keys + 8 pad]
  __shared__ unsigned short Psm[8 * 32 * 72];   // per wave [32 q][64 keys + 8 pad]

  const int bid = blockIdx.x;
  const int h = bid & 15;
  const int c = (bid >> 4) & 31;
  const int b = bid >> 9;
  const int tid = threadIdx.x;
  const int wid = tid >> 6, lane = tid & 63;
  const int lo = lane & 15, hi = lane >> 4;
  const float SCALE = 0.08838834764831845f;  // 1/sqrt(128)

  // hoist Q fragments into registers
  bf16x8 qf[2][4];
  {
    const size_t base = ((size_t)(b * SEQ + c * WINW + wid * 32 + lo)) * DIMS + h * HD;
    #pragma unroll
    for (int m = 0; m < 2; ++m)
      #pragma unroll
      for (int ks = 0; ks < 4; ++ks)
        qf[m][ks] = *(const bf16x8*)&Qb[base + (size_t)m * 16 * DIMS + ks * 32 + hi * 8];
  }

  f32x4 O[2][8];
  float mrow[2][4], lrow[2][4];
  #pragma unroll
  for (int m = 0; m < 2; ++m) {
    #pragma unroll
    for (int n = 0; n < 8; ++n) O[m][n] = (f32x4){0.f, 0.f, 0.f, 0.f};
    #pragma unroll
    for (int r = 0; r < 4; ++r) { mrow[m][r] = -INFINITY; lrow[m][r] = 0.f; }
  }

  unsigned short* Pw = Psm + wid * 32 * 72;
  const int t0 = (c == 0) ? 4 : 0;  // block-uniform: skip prev-chunk tiles for chunk 0

  for (int t = t0; t < 8; ++t) {
    const int krow_base = b * SEQ + (c - 1) * WINW + t * 64;  // absolute seq row of tile key 0
    // stage K [64][128] (vector) and V transposed [128][64]
    #pragma unroll
    for (int i = 0; i < 2; ++i) {
      const int cid = i * 512 + tid;
      const int kr = cid >> 4;
      const int d8 = (cid & 15) << 3;
      *(bf16x8*)&Ksm[kr * 136 + d8] =
          *(const bf16x8*)&Kb[(size_t)(krow_base + kr) * DIMS + h * HD + d8];
      bf16x8 v = *(const bf16x8*)&Vb[(size_t)(krow_base + kr) * DIMS + h * HD + d8];
      #pragma unroll
      for (int e = 0; e < 8; ++e)
        Vsm[(d8 + e) * 72 + kr] = (unsigned short)v[e];
    }
    __syncthreads();

    // S = Q @ K^T  (64 keys)
    f32x4 S[2][4];
    #pragma unroll
    for (int m = 0; m < 2; ++m)
      #pragma unroll
      for (int n = 0; n < 4; ++n)
        S[m][n] = (f32x4){0.f, 0.f, 0.f, 0.f};
    #pragma unroll
    for (int ks = 0; ks < 4; ++ks) {
      const int ko = ks * 32 + hi * 8;
      bf16x8 kf[4];
      #pragma unroll
      for (int n = 0; n < 4; ++n)
        kf[n] = *(const bf16x8*)&Ksm[(n * 16 + lo) * 136 + ko];
      #pragma unroll
      for (int m = 0; m < 2; ++m)
        #pragma unroll
        for (int n = 0; n < 4; ++n)
          S[m][n] = __builtin_amdgcn_mfma_f32_16x16x32_bf16(qf[m][ks], kf[n], S[m][n], 0, 0, 0);
    }

    // mask + online softmax
    #pragma unroll
    for (int m = 0; m < 2; ++m) {
      #pragma unroll
      for (int r = 0; r < 4; ++r) {
        const int qrow = wid * 32 + m * 16 + hi * 4 + r;
        float tmax = -INFINITY;
        #pragma unroll
        for (int n = 0; n < 4; ++n) {
          const int kc = t * 64 + n * 16 + lo;
          float v = S[m][n][r] * SCALE;
          const bool ok = (kc < WINW) ? (c > 0) : ((kc - WINW) <= qrow);
          v = ok ? v : -INFINITY;
          S[m][n][r] = v;
          tmax = fmaxf(tmax, v);
        }
        tmax = fmaxf(tmax, __shfl_xor(tmax, 1));
        tmax = fmaxf(tmax, __shfl_xor(tmax, 2));
        tmax = fmaxf(tmax, __shfl_xor(tmax, 4));
        tmax = fmaxf(tmax, __shfl_xor(tmax, 8));
        const float mold = mrow[m][r];
        const float mnew = fmaxf(mold, tmax);
        const float corr = __expf(mold - mnew);
        float rsum = 0.f;
        #pragma unroll
        for (int n = 0; n < 4; ++n) {
          const float p = __expf(S[m][n][r] - mnew);
          S[m][n][r] = p;
          rsum += p;
        }
        rsum += __shfl_xor(rsum, 1);
        rsum += __shfl_xor(rsum, 2);
        rsum += __shfl_xor(rsum, 4);
        rsum += __shfl_xor(rsum, 8);
        mrow[m][r] = mnew;
        lrow[m][r] = lrow[m][r] * corr + rsum;
        #pragma unroll
        for (int n = 0; n < 8; ++n) O[m][n][r] *= corr;
        #pragma unroll
        for (int n = 0; n < 4; ++n)
          Pw[(m * 16 + hi * 4 + r) * 72 + n * 16 + lo] = f2bf(S[m][n][r]);
      }
    }
    asm volatile("" ::: "memory");  // keep P stores before P reads (DS is in-order per wave)

    // O += P @ V
    #pragma unroll
    for (int kk = 0; kk < 2; ++kk) {
      const int ko = kk * 32 + hi * 8;
      bf16x8 pf[2], vf[8];
      #pragma unroll
      for (int m = 0; m < 2; ++m)
        pf[m] = *(const bf16x8*)&Pw[(m * 16 + lo) * 72 + ko];
      #pragma unroll
      for (int n = 0; n < 8; ++n)
        vf[n] = *(const bf16x8*)&Vsm[(n * 16 + lo) * 72 + ko];
      #pragma unroll
      for (int m = 0; m < 2; ++m)
        #pragma unroll
        for (int n = 0; n < 8; ++n)
          O[m][n] = __builtin_amdgcn_mfma_f32_16x16x32_bf16(pf[m], vf[n], O[m][n], 0, 0, 0);
    }
    __syncthreads();
  }

  // normalize + write bf16 attention output [B,S,H*D]
  #pragma unroll
  for (int m = 0; m < 2; ++m) {
    #pragma unroll
    for (int r = 0; r < 4; ++r) {
      const float inv = 1.f / lrow[m][r];
      const size_t row = (size_t)(b * SEQ + c * WINW + wid * 32 + m * 16 + hi * 4 + r);
      unsigned short* o = AO + row * DIMS + h * HD;
      #pragma unroll
      for (int n = 0; n < 8; ++n)
        o[n * 16 + lo] = f2bf(O[m][n][r] * inv);
    }
  }
}

extern "C" void kernel_launch(void* const* d_in, const int* in_sizes, int n_in,
                              void* d_out, int out_size, void* d_ws, size_t ws_size,
                              hipStream_t stream) {
  const float* H  = (const float*)d_in[0];
  const float* Wq = (const float*)d_in[1];
  const float* Wk = (const float*)d_in[2];
  const float* Wv = (const float*)d_in[3];
  const float* Wo = (const float*)d_in[4];
  float* out = (float*)d_out;

  // workspace layout (373.3 MB total)
  unsigned short* Wt  = (unsigned short*)d_ws;                  // 4*2048*2048 bf16
  unsigned short* Hb  = Wt + (size_t)4 * DIMS * DIMS;           // 16384*2048 bf16
  unsigned short* QKV = Hb + (size_t)MROWS * DIMS;              // 3 x 16384*2048 bf16
  unsigned short* AO  = QKV + (size_t)3 * MROWS * DIMS;         // 16384*2048 bf16
  float* cosT = (float*)(AO + (size_t)MROWS * DIMS);            // 8192*64 f32
  float* sinT = cosT + (size_t)SEQ * 64;

  wconv<<<dim3(32, 32, 4), 256, 0, stream>>>(Wq, Wk, Wv, Wo, Wt);
  hconv<<<2048, 256, 0, stream>>>(H, Hb);
  rope_tab<<<2048, 256, 0, stream>>>(cosT, sinT);
  gemm_bt<0><<<dim3(16, 128, 3), 256, 0, stream>>>(Hb, Wt, QKV, nullptr, cosT, sinT);
  attn<<<dim3(1024), 512, 0, stream>>>(QKV, QKV + (size_t)MROWS * DIMS,
                                       QKV + (size_t)2 * MROWS * DIMS, AO);
  gemm_bt<1><<<dim3(16, 128, 1), 256, 0, stream>>>(AO, Wt, nullptr, out, cosT, sinT);
}

// Round 2
// 871.669 us; speedup vs baseline: 1.2919x; 1.2919x over previous
//
#include <hip/hip_runtime.h>
#include <cmath>

#define DIMS 2048
#define SEQ  8192
#define NB   2
#define HEADS 16
#define HD   128
#define WINW 256
#define MROWS 16384  // NB*SEQ
#define NCH  32      // SEQ/WINW

using bf16x8 = __attribute__((ext_vector_type(8))) short;
using f32x4  = __attribute__((ext_vector_type(4))) float;

__device__ __forceinline__ unsigned short f2bf(float f) {
  unsigned int u = __float_as_uint(f);
  u += 0x7FFF + ((u >> 16) & 1);
  return (unsigned short)(u >> 16);
}

__device__ __forceinline__ void async16(const unsigned short* g, unsigned short* l) {
  __builtin_amdgcn_global_load_lds((const __attribute__((address_space(1))) void*)g,
                                   (__attribute__((address_space(3))) void*)l,
                                   16, 0, 0);
}

#define BAR() __builtin_amdgcn_s_barrier()
#define WAIT_LGKM0() do { asm volatile("s_waitcnt lgkmcnt(0)" ::: "memory"); \
                          __builtin_amdgcn_sched_barrier(0); } while (0)
#define WAIT_VM(n) asm volatile("s_waitcnt vmcnt(" #n ")" ::: "memory")
#define MFMA16(a, b, c) __builtin_amdgcn_mfma_f32_16x16x32_bf16(a, b, c, 0, 0, 0)

// ---------------- weight transpose+convert: W[K,N] f32 -> Wt[N,K] bf16 ----------------
__global__ void wconv(const float* __restrict__ w0, const float* __restrict__ w1,
                      const float* __restrict__ w2, const float* __restrict__ w3,
                      unsigned short* __restrict__ Wt) {
  __shared__ unsigned short tile[64][65];
  const float* W = (blockIdx.z == 0) ? w0 : (blockIdx.z == 1) ? w1 : (blockIdx.z == 2) ? w2 : w3;
  unsigned short* O = Wt + (size_t)blockIdx.z * DIMS * DIMS;
  const int k0 = blockIdx.y * 64, n0 = blockIdx.x * 64;
  const int t = threadIdx.x;
  #pragma unroll
  for (int p = 0; p < 16; ++p) {
    int i = p * 4 + (t >> 6);
    int j = t & 63;
    tile[i][j] = f2bf(W[(size_t)(k0 + i) * DIMS + n0 + j]);
  }
  __syncthreads();
  #pragma unroll
  for (int p = 0; p < 16; ++p) {
    int a = p * 4 + (t >> 6);
    int b = t & 63;
    O[(size_t)(n0 + a) * DIMS + k0 + b] = tile[b][a];
  }
}

// ---------------- hidden f32 -> bf16 ----------------
__global__ void hconv(const float* __restrict__ in, unsigned short* __restrict__ outp) {
  const long n4 = (long)MROWS * DIMS / 4;
  long i = (long)blockIdx.x * blockDim.x + threadIdx.x;
  const long stride = (long)gridDim.x * blockDim.x;
  for (; i < n4; i += stride) {
    float4 v = ((const float4*)in)[i];
    ushort4 o;
    o.x = f2bf(v.x); o.y = f2bf(v.y); o.z = f2bf(v.z); o.w = f2bf(v.w);
    ((ushort4*)outp)[i] = o;
  }
}

// ---------------- RoPE table: [8192][64] cos/sin ----------------
__global__ void rope_tab(float* __restrict__ cosT, float* __restrict__ sinT) {
  int t = blockIdx.x * 256 + threadIdx.x;  // 524288 total
  int pos = t >> 6, i = t & 63;
  double inv = pow(10000.0, -(double)i / 64.0);
  double ang = (double)pos * inv;
  cosT[t] = (float)cos(ang);
  sinT[t] = (float)sin(ang);
}

// ---------------- 256x256 8-phase GEMM: A[M,K]bf16 @ Bt[N,K]^T ----------------
// 512 thr = 8 waves (2M x 4N), BK=64, LDS 128KB double-buffered, st_16x32 swizzle.
// Wave stripe ownership: M-frag i at row i*32+wm*16 (i<4 -> A-half0), N-frag j at
// col j*64+wn*16 (j<2 -> B-half0) => phase (qm,qn) reads exactly halves (qm, qn).
// MODE 0: QKV (bf16 out, RoPE when z<2).  MODE 1: O-proj (f32 out to d_out).
template<int MODE>
__global__ __launch_bounds__(512, 2) void gemm256(
    const unsigned short* __restrict__ A,
    const unsigned short* __restrict__ WtAll,
    unsigned short* __restrict__ OutB,
    float* __restrict__ OutF,
    const float* __restrict__ cosT,
    const float* __restrict__ sinT) {
  __shared__ __align__(1024) unsigned short lds[65536];  // 128 KiB
  unsigned short* const As0 = lds;           // buf0 A [256][64]
  unsigned short* const Bs0 = lds + 16384;   // buf0 B
  unsigned short* const As1 = lds + 32768;   // buf1 A
  unsigned short* const Bs1 = lds + 49152;   // buf1 B

  const int tid = threadIdx.x;
  const int wid = tid >> 6, lane = tid & 63;
  const int lo = lane & 15, hi = lane >> 4;
  const int wm = wid >> 2, wn = wid & 3;
  const int flip = ((lo >> 2) & 1) << 5;  // st_16x32 read-side XOR (byte bit5 ^ bit9)

  const int bid = blockIdx.x;
  const int z = (MODE == 0) ? (bid >> 9) : 3;
  const int by = (MODE == 0) ? ((bid & 511) >> 3) : (bid >> 3);
  const int bx = bid & 7;
  const int m0 = by * 256, n0 = bx * 256;
  const unsigned short* const Ag = A;
  const unsigned short* const Bg = WtAll + (size_t)z * DIMS * DIMS;

  f32x4 acc[8][4];
  #pragma unroll
  for (int i = 0; i < 8; ++i)
    #pragma unroll
    for (int j = 0; j < 4; ++j)
      acc[i][j] = (f32x4){0.f, 0.f, 0.f, 0.f};

  // stage one 128-row half-tile (16 KB): linear LDS dest, inverse-swizzled source.
  auto stage_half = [&](const unsigned short* __restrict__ G, int grow0, int tile,
                        unsigned short* dst) {
    const int k0 = tile * 64;
    #pragma unroll
    for (int h8 = 0; h8 < 2; ++h8) {
      const int c = h8 * 8 + wid;
      const int row = c * 8 + (lane >> 3);
      const int col8 = (lane & 7) ^ (((lane >> 5) & 1) << 1);
      async16(G + (size_t)(grow0 + row) * DIMS + k0 + col8 * 8, dst + c * 512);
    }
  };
  auto rdA = [&](const unsigned short* base, int i, int kk) -> bf16x8 {
    const int r = i * 32 + wm * 16 + lo;
    const int cb = (kk * 64 + hi * 16) ^ flip;
    return *(const bf16x8*)((const char*)base + r * 128 + cb);
  };
  auto rdB = [&](const unsigned short* base, int j, int kk) -> bf16x8 {
    const int r = j * 64 + wn * 16 + lo;
    const int cb = (kk * 64 + hi * 16) ^ flip;
    return *(const bf16x8*)((const char*)base + r * 128 + cb);
  };

  bf16x8 aq[4][2], b0[2][2], b1[2][2];

  // prologue: tile0 full + {A0,B0,B1}(1); vmcnt(6) => tile0 landed, 3 halves in flight
  stage_half(Ag, m0,       0, As0);
  stage_half(Bg, n0,       0, Bs0);
  stage_half(Ag, m0 + 128, 0, As0 + 8192);
  stage_half(Bg, n0 + 128, 0, Bs0 + 8192);
  stage_half(Ag, m0,       1, As1);
  stage_half(Bg, n0,       1, Bs1);
  stage_half(Bg, n0 + 128, 1, Bs1 + 8192);
  WAIT_VM(6);
  BAR();

  #pragma unroll 1
  for (int it = 0; it < 16; ++it) {
    const int t = 2 * it;
    const bool pre = (it < 15);
    // ---- P1: read A0,B0(buf0); stage A1(t+1)->buf1; MFMA (qm0,qn0)
    #pragma unroll
    for (int i = 0; i < 4; ++i) { aq[i][0] = rdA(As0, i, 0); aq[i][1] = rdA(As0, i, 1); }
    #pragma unroll
    for (int j = 0; j < 2; ++j) { b0[j][0] = rdB(Bs0, j, 0); b0[j][1] = rdB(Bs0, j, 1); }
    stage_half(Ag, m0 + 128, t + 1, As1 + 8192);
    BAR(); WAIT_LGKM0();
    __builtin_amdgcn_s_setprio(1);
    #pragma unroll
    for (int kk = 0; kk < 2; ++kk)
      #pragma unroll
      for (int i = 0; i < 4; ++i)
        #pragma unroll
        for (int j = 0; j < 2; ++j)
          acc[i][j] = MFMA16(aq[i][kk], b0[j][kk], acc[i][j]);
    __builtin_amdgcn_s_setprio(0);
    BAR();
    // ---- P2: read B1(buf0); stage A0(t+2)->buf0; MFMA (qm0,qn1)
    #pragma unroll
    for (int j = 0; j < 2; ++j) { b1[j][0] = rdB(Bs0, 2 + j, 0); b1[j][1] = rdB(Bs0, 2 + j, 1); }
    if (pre) stage_half(Ag, m0, t + 2, As0);
    BAR(); WAIT_LGKM0();
    __builtin_amdgcn_s_setprio(1);
    #pragma unroll
    for (int kk = 0; kk < 2; ++kk)
      #pragma unroll
      for (int i = 0; i < 4; ++i)
        #pragma unroll
        for (int j = 0; j < 2; ++j)
          acc[i][2 + j] = MFMA16(aq[i][kk], b1[j][kk], acc[i][2 + j]);
    __builtin_amdgcn_s_setprio(0);
    BAR();
    // ---- P3: read A1(buf0) into aq; stage B0(t+2)->buf0; MFMA (qm1,qn0)
    #pragma unroll
    for (int i = 0; i < 4; ++i) { aq[i][0] = rdA(As0, 4 + i, 0); aq[i][1] = rdA(As0, 4 + i, 1); }
    if (pre) stage_half(Bg, n0, t + 2, Bs0);
    BAR(); WAIT_LGKM0();
    __builtin_amdgcn_s_setprio(1);
    #pragma unroll
    for (int kk = 0; kk < 2; ++kk)
      #pragma unroll
      for (int i = 0; i < 4; ++i)
        #pragma unroll
        for (int j = 0; j < 2; ++j)
          acc[4 + i][j] = MFMA16(aq[i][kk], b0[j][kk], acc[4 + i][j]);
    __builtin_amdgcn_s_setprio(0);
    BAR();
    // ---- P4: stage B1(t+2)->buf0; MFMA (qm1,qn1); counted vmcnt
    if (pre) stage_half(Bg, n0 + 128, t + 2, Bs0 + 8192);
    BAR();
    __builtin_amdgcn_s_setprio(1);
    #pragma unroll
    for (int kk = 0; kk < 2; ++kk)
      #pragma unroll
      for (int i = 0; i < 4; ++i)
        #pragma unroll
        for (int j = 0; j < 2; ++j)
          acc[4 + i][2 + j] = MFMA16(aq[i][kk], b1[j][kk], acc[4 + i][2 + j]);
    __builtin_amdgcn_s_setprio(0);
    if (it == 15) { WAIT_VM(0); } else { WAIT_VM(6); }
    BAR();
    // ---- P5: read A0,B0(buf1); stage A1(t+2)->buf0; MFMA (qm0,qn0) of t+1
    #pragma unroll
    for (int i = 0; i < 4; ++i) { aq[i][0] = rdA(As1, i, 0); aq[i][1] = rdA(As1, i, 1); }
    #pragma unroll
    for (int j = 0; j < 2; ++j) { b0[j][0] = rdB(Bs1, j, 0); b0[j][1] = rdB(Bs1, j, 1); }
    if (pre) stage_half(Ag, m0 + 128, t + 2, As0 + 8192);
    BAR(); WAIT_LGKM0();
    __builtin_amdgcn_s_setprio(1);
    #pragma unroll
    for (int kk = 0; kk < 2; ++kk)
      #pragma unroll
      for (int i = 0; i < 4; ++i)
        #pragma unroll
        for (int j = 0; j < 2; ++j)
          acc[i][j] = MFMA16(aq[i][kk], b0[j][kk], acc[i][j]);
    __builtin_amdgcn_s_setprio(0);
    BAR();
    // ---- P6: read B1(buf1); stage A0(t+3)->buf1; MFMA (qm0,qn1)
    #pragma unroll
    for (int j = 0; j < 2; ++j) { b1[j][0] = rdB(Bs1, 2 + j, 0); b1[j][1] = rdB(Bs1, 2 + j, 1); }
    if (pre) stage_half(Ag, m0, t + 3, As1);
    BAR(); WAIT_LGKM0();
    __builtin_amdgcn_s_setprio(1);
    #pragma unroll
    for (int kk = 0; kk < 2; ++kk)
      #pragma unroll
      for (int i = 0; i < 4; ++i)
        #pragma unroll
        for (int j = 0; j < 2; ++j)
          acc[i][2 + j] = MFMA16(aq[i][kk], b1[j][kk], acc[i][2 + j]);
    __builtin_amdgcn_s_setprio(0);
    BAR();
    // ---- P7: read A1(buf1); stage B0(t+3)->buf1; MFMA (qm1,qn0)
    #pragma unroll
    for (int i = 0; i < 4; ++i) { aq[i][0] = rdA(As1, 4 + i, 0); aq[i][1] = rdA(As1, 4 + i, 1); }
    if (pre) stage_half(Bg, n0, t + 3, Bs1);
    BAR(); WAIT_LGKM0();
    __builtin_amdgcn_s_setprio(1);
    #pragma unroll
    for (int kk = 0; kk < 2; ++kk)
      #pragma unroll
      for (int i = 0; i < 4; ++i)
        #pragma unroll
        for (int j = 0; j < 2; ++j)
          acc[4 + i][j] = MFMA16(aq[i][kk], b0[j][kk], acc[4 + i][j]);
    __builtin_amdgcn_s_setprio(0);
    BAR();
    // ---- P8: stage B1(t+3)->buf1; MFMA (qm1,qn1); counted vmcnt
    if (pre) stage_half(Bg, n0 + 128, t + 3, Bs1 + 8192);
    BAR();
    __builtin_amdgcn_s_setprio(1);
    #pragma unroll
    for (int kk = 0; kk < 2; ++kk)
      #pragma unroll
      for (int i = 0; i < 4; ++i)
        #pragma unroll
        for (int j = 0; j < 2; ++j)
          acc[4 + i][2 + j] = MFMA16(aq[i][kk], b1[j][kk], acc[4 + i][2 + j]);
    __builtin_amdgcn_s_setprio(0);
    WAIT_VM(6);
    BAR();
  }

  // epilogue
  const int rope = (MODE == 0) && (z < 2);
  unsigned short* outb = (MODE == 0) ? (OutB + (size_t)z * MROWS * DIMS) : (unsigned short*)nullptr;
  #pragma unroll
  for (int i = 0; i < 8; ++i) {
    #pragma unroll
    for (int rr = 0; rr < 4; ++rr) {
      const int row = m0 + i * 32 + wm * 16 + hi * 4 + rr;
      const int s = row & (SEQ - 1);
      if (MODE == 1) {
        float* o = OutF + (size_t)row * DIMS + n0;
        #pragma unroll
        for (int j = 0; j < 4; ++j) o[j * 64 + wn * 16 + lo] = acc[i][j][rr];
      } else if (rope) {
        unsigned short* o = outb + (size_t)row * DIMS + n0;
        const int d = wn * 16 + lo;  // < 64
        const float c = cosT[s * 64 + d], sn = sinT[s * 64 + d];
        #pragma unroll
        for (int p = 0; p < 2; ++p) {  // p=0: head n0/128, p=1: head n0/128+1
          const float v1 = acc[i][2 * p][rr], v2 = acc[i][2 * p + 1][rr];
          o[p * 128 + d]      = f2bf(v1 * c - v2 * sn);
          o[p * 128 + d + 64] = f2bf(v2 * c + v1 * sn);
        }
      } else {
        unsigned short* o = outb + (size_t)row * DIMS + n0;
        #pragma unroll
        for (int j = 0; j < 4; ++j) o[j * 64 + wn * 16 + lo] = f2bf(acc[i][j][rr]);
      }
    }
  }
}

// ---------------- block sliding-window attention ----------------
// grid: B*C*H = 1024 blocks; block = 512 threads = 8 waves; wave = 32 q-rows.
__global__ __launch_bounds__(512) void attn(
    const unsigned short* __restrict__ Qb,
    const unsigned short* __restrict__ Kb,
    const unsigned short* __restrict__ Vb,
    unsigned short* __restrict__ AO) {
  __shared__ unsigned short Ksm[64 * 136];      // [64 keys][128 d + 8 pad]
  __shared__ unsigned short Vsm[128 * 72];      // V^T: [128 d][64 keys + 8 pad]
  __shared__ unsigned short Psm[8 * 32 * 72];   // per wave [32 q][64 keys + 8 pad]

  const int bid = blockIdx.x;
  const int h = bid & 15;
  const int c = (bid >> 4) & 31;
  const int b = bid >> 9;
  const int tid = threadIdx.x;
  const int wid = tid >> 6, lane = tid & 63;
  const int lo = lane & 15, hi = lane >> 4;
  const float SCALE = 0.08838834764831845f;  // 1/sqrt(128)

  // hoist Q fragments into registers
  bf16x8 qf[2][4];
  {
    const size_t base = ((size_t)(b * SEQ + c * WINW + wid * 32 + lo)) * DIMS + h * HD;
    #pragma unroll
    for (int m = 0; m < 2; ++m)
      #pragma unroll
      for (int ks = 0; ks < 4; ++ks)
        qf[m][ks] = *(const bf16x8*)&Qb[base + (size_t)m * 16 * DIMS + ks * 32 + hi * 8];
  }

  f32x4 O[2][8];
  float mrow[2][4], lrow[2][4];
  #pragma unroll
  for (int m = 0; m < 2; ++m) {
    #pragma unroll
    for (int n = 0; n < 8; ++n) O[m][n] = (f32x4){0.f, 0.f, 0.f, 0.f};
    #pragma unroll
    for (int r = 0; r < 4; ++r) { mrow[m][r] = -INFINITY; lrow[m][r] = 0.f; }
  }

  unsigned short* Pw = Psm + wid * 32 * 72;
  const int t0 = (c == 0) ? 4 : 0;  // block-uniform: skip prev-chunk tiles for chunk 0

  for (int t = t0; t < 8; ++t) {
    const int krow_base = b * SEQ + (c - 1) * WINW + t * 64;  // absolute seq row of tile key 0
    // stage K [64][128] (vector) and V transposed [128][64]
    #pragma unroll
    for (int i = 0; i < 2; ++i) {
      const int cid = i * 512 + tid;
      const int kr = cid >> 4;
      const int d8 = (cid & 15) << 3;
      *(bf16x8*)&Ksm[kr * 136 + d8] =
          *(const bf16x8*)&Kb[(size_t)(krow_base + kr) * DIMS + h * HD + d8];
      bf16x8 v = *(const bf16x8*)&Vb[(size_t)(krow_base + kr) * DIMS + h * HD + d8];
      #pragma unroll
      for (int e = 0; e < 8; ++e)
        Vsm[(d8 + e) * 72 + kr] = (unsigned short)v[e];
    }
    __syncthreads();

    // S = Q @ K^T  (64 keys)
    f32x4 S[2][4];
    #pragma unroll
    for (int m = 0; m < 2; ++m)
      #pragma unroll
      for (int n = 0; n < 4; ++n)
        S[m][n] = (f32x4){0.f, 0.f, 0.f, 0.f};
    #pragma unroll
    for (int ks = 0; ks < 4; ++ks) {
      const int ko = ks * 32 + hi * 8;
      bf16x8 kf[4];
      #pragma unroll
      for (int n = 0; n < 4; ++n)
        kf[n] = *(const bf16x8*)&Ksm[(n * 16 + lo) * 136 + ko];
      #pragma unroll
      for (int m = 0; m < 2; ++m)
        #pragma unroll
        for (int n = 0; n < 4; ++n)
          S[m][n] = __builtin_amdgcn_mfma_f32_16x16x32_bf16(qf[m][ks], kf[n], S[m][n], 0, 0, 0);
    }

    // mask + online softmax
    #pragma unroll
    for (int m = 0; m < 2; ++m) {
      #pragma unroll
      for (int r = 0; r < 4; ++r) {
        const int qrow = wid * 32 + m * 16 + hi * 4 + r;
        float tmax = -INFINITY;
        #pragma unroll
        for (int n = 0; n < 4; ++n) {
          const int kc = t * 64 + n * 16 + lo;
          float v = S[m][n][r] * SCALE;
          const bool ok = (kc < WINW) ? (c > 0) : ((kc - WINW) <= qrow);
          v = ok ? v : -INFINITY;
          S[m][n][r] = v;
          tmax = fmaxf(tmax, v);
        }
        tmax = fmaxf(tmax, __shfl_xor(tmax, 1));
        tmax = fmaxf(tmax, __shfl_xor(tmax, 2));
        tmax = fmaxf(tmax, __shfl_xor(tmax, 4));
        tmax = fmaxf(tmax, __shfl_xor(tmax, 8));
        const float mold = mrow[m][r];
        const float mnew = fmaxf(mold, tmax);
        const float corr = __expf(mold - mnew);
        float rsum = 0.f;
        #pragma unroll
        for (int n = 0; n < 4; ++n) {
          const float p = __expf(S[m][n][r] - mnew);
          S[m][n][r] = p;
          rsum += p;
        }
        rsum += __shfl_xor(rsum, 1);
        rsum += __shfl_xor(rsum, 2);
        rsum += __shfl_xor(rsum, 4);
        rsum += __shfl_xor(rsum, 8);
        mrow[m][r] = mnew;
        lrow[m][r] = lrow[m][r] * corr + rsum;
        #pragma unroll
        for (int n = 0; n < 8; ++n) O[m][n][r] *= corr;
        #pragma unroll
        for (int n = 0; n < 4; ++n)
          Pw[(m * 16 + hi * 4 + r) * 72 + n * 16 + lo] = f2bf(S[m][n][r]);
      }
    }
    asm volatile("" ::: "memory");  // keep P stores before P reads (DS is in-order per wave)

    // O += P @ V
    #pragma unroll
    for (int kk = 0; kk < 2; ++kk) {
      const int ko = kk * 32 + hi * 8;
      bf16x8 pf[2], vf[8];
      #pragma unroll
      for (int m = 0; m < 2; ++m)
        pf[m] = *(const bf16x8*)&Pw[(m * 16 + lo) * 72 + ko];
      #pragma unroll
      for (int n = 0; n < 8; ++n)
        vf[n] = *(const bf16x8*)&Vsm[(n * 16 + lo) * 72 + ko];
      #pragma unroll
      for (int m = 0; m < 2; ++m)
        #pragma unroll
        for (int n = 0; n < 8; ++n)
          O[m][n] = __builtin_amdgcn_mfma_f32_16x16x32_bf16(pf[m], vf[n], O[m][n], 0, 0, 0);
    }
    __syncthreads();
  }

  // normalize + write bf16 attention output [B,S,H*D]
  #pragma unroll
  for (int m = 0; m < 2; ++m) {
    #pragma unroll
    for (int r = 0; r < 4; ++r) {
      const float inv = 1.f / lrow[m][r];
      const size_t row = (size_t)(b * SEQ + c * WINW + wid * 32 + m * 16 + hi * 4 + r);
      unsigned short* o = AO + row * DIMS + h * HD;
      #pragma unroll
      for (int n = 0; n < 8; ++n)
        o[n * 16 + lo] = f2bf(O[m][n][r] * inv);
    }
  }
}

extern "C" void kernel_launch(void* const* d_in, const int* in_sizes, int n_in,
                              void* d_out, int out_size, void* d_ws, size_t ws_size,
                              hipStream_t stream) {
  const float* H  = (const float*)d_in[0];
  const float* Wq = (const float*)d_in[1];
  const float* Wk = (const float*)d_in[2];
  const float* Wv = (const float*)d_in[3];
  const float* Wo = (const float*)d_in[4];
  float* out = (float*)d_out;

  // workspace layout (373.3 MB total)
  unsigned short* Wt  = (unsigned short*)d_ws;                  // 4*2048*2048 bf16
  unsigned short* Hb  = Wt + (size_t)4 * DIMS * DIMS;           // 16384*2048 bf16
  unsigned short* QKV = Hb + (size_t)MROWS * DIMS;              // 3 x 16384*2048 bf16
  unsigned short* AO  = QKV + (size_t)3 * MROWS * DIMS;         // 16384*2048 bf16
  float* cosT = (float*)(AO + (size_t)MROWS * DIMS);            // 8192*64 f32
  float* sinT = cosT + (size_t)SEQ * 64;

  wconv<<<dim3(32, 32, 4), 256, 0, stream>>>(Wq, Wk, Wv, Wo, Wt);
  hconv<<<2048, 256, 0, stream>>>(H, Hb);
  rope_tab<<<2048, 256, 0, stream>>>(cosT, sinT);
  gemm256<0><<<1536, 512, 0, stream>>>(Hb, Wt, QKV, nullptr, cosT, sinT);
  attn<<<dim3(1024), 512, 0, stream>>>(QKV, QKV + (size_t)MROWS * DIMS,
                                       QKV + (size_t)2 * MROWS * DIMS, AO);
  gemm256<1><<<512, 512, 0, stream>>>(AO, Wt, nullptr, out, cosT, sinT);
}

// Round 3
// 816.959 us; speedup vs baseline: 1.3784x; 1.0670x over previous
//
#include <hip/hip_runtime.h>
#include <cmath>

#define DIMS 2048
#define SEQ  8192
#define NB   2
#define HEADS 16
#define HD   128
#define WINW 256
#define MROWS 16384  // NB*SEQ
#define NCH  32      // SEQ/WINW

using bf16x8 = __attribute__((ext_vector_type(8))) short;
using f32x4  = __attribute__((ext_vector_type(4))) float;

__device__ __forceinline__ unsigned short f2bf(float f) {
  unsigned int u = __float_as_uint(f);
  u += 0x7FFF + ((u >> 16) & 1);
  return (unsigned short)(u >> 16);
}

__device__ __forceinline__ void async16(const unsigned short* g, unsigned short* l) {
  __builtin_amdgcn_global_load_lds((const __attribute__((address_space(1))) void*)g,
                                   (__attribute__((address_space(3))) void*)l,
                                   16, 0, 0);
}

#define BAR() __builtin_amdgcn_s_barrier()
#define WAIT_LGKM0() do { asm volatile("s_waitcnt lgkmcnt(0)" ::: "memory"); \
                          __builtin_amdgcn_sched_barrier(0); } while (0)
#define WAIT_VM(n) asm volatile("s_waitcnt vmcnt(" #n ")" ::: "memory")
#define MFMA16(a, b, c) __builtin_amdgcn_mfma_f32_16x16x32_bf16(a, b, c, 0, 0, 0)

// ---------------- weight transpose+convert: W[K,N] f32 -> Wt[N,K] bf16 ----------------
__global__ void wconv(const float* __restrict__ w0, const float* __restrict__ w1,
                      const float* __restrict__ w2, const float* __restrict__ w3,
                      unsigned short* __restrict__ Wt) {
  __shared__ unsigned short tile[64][65];
  const float* W = (blockIdx.z == 0) ? w0 : (blockIdx.z == 1) ? w1 : (blockIdx.z == 2) ? w2 : w3;
  unsigned short* O = Wt + (size_t)blockIdx.z * DIMS * DIMS;
  const int k0 = blockIdx.y * 64, n0 = blockIdx.x * 64;
  const int t = threadIdx.x;
  #pragma unroll
  for (int p = 0; p < 16; ++p) {
    int i = p * 4 + (t >> 6);
    int j = t & 63;
    tile[i][j] = f2bf(W[(size_t)(k0 + i) * DIMS + n0 + j]);
  }
  __syncthreads();
  #pragma unroll
  for (int p = 0; p < 16; ++p) {
    int a = p * 4 + (t >> 6);
    int b = t & 63;
    O[(size_t)(n0 + a) * DIMS + k0 + b] = tile[b][a];
  }
}

// ---------------- hidden f32 -> bf16 ----------------
__global__ void hconv(const float* __restrict__ in, unsigned short* __restrict__ outp) {
  const long n4 = (long)MROWS * DIMS / 4;
  long i = (long)blockIdx.x * blockDim.x + threadIdx.x;
  const long stride = (long)gridDim.x * blockDim.x;
  for (; i < n4; i += stride) {
    float4 v = ((const float4*)in)[i];
    ushort4 o;
    o.x = f2bf(v.x); o.y = f2bf(v.y); o.z = f2bf(v.z); o.w = f2bf(v.w);
    ((ushort4*)outp)[i] = o;
  }
}

// ---------------- RoPE table: [8192][64] cos/sin ----------------
__global__ void rope_tab(float* __restrict__ cosT, float* __restrict__ sinT) {
  int t = blockIdx.x * 256 + threadIdx.x;  // 524288 total
  int pos = t >> 6, i = t & 63;
  double inv = pow(10000.0, -(double)i / 64.0);
  double ang = (double)pos * inv;
  cosT[t] = (float)cos(ang);
  sinT[t] = (float)sin(ang);
}

// ---------------- 256x256 8-phase GEMM: A[M,K]bf16 @ Bt[N,K]^T ----------------
// 512 thr = 8 waves (2M x 4N), BK=64, LDS 128KB double-buffered.
// LDS swizzle: byte ^= (row&7)<<4 (read side); inverse-swizzled global source with
// linear global_load_lds dest (rule 21). Conflict-free: each 8-lane group reads a
// permutation of the 8 16B column slots.
// MODE 0: QKV (bf16 out, RoPE when z<2).  MODE 1: O-proj (f32 out to d_out).
template<int MODE>
__global__ __launch_bounds__(512, 2) void gemm256(
    const unsigned short* __restrict__ A,
    const unsigned short* __restrict__ WtAll,
    unsigned short* __restrict__ OutB,
    float* __restrict__ OutF,
    const float* __restrict__ cosT,
    const float* __restrict__ sinT) {
  __shared__ __align__(1024) unsigned short lds[65536];  // 128 KiB
  unsigned short* const As0 = lds;           // buf0 A [256][64]
  unsigned short* const Bs0 = lds + 16384;   // buf0 B
  unsigned short* const As1 = lds + 32768;   // buf1 A
  unsigned short* const Bs1 = lds + 49152;   // buf1 B

  const int tid = threadIdx.x;
  const int wid = tid >> 6, lane = tid & 63;
  const int lo = lane & 15, hi = lane >> 4;
  const int wm = wid >> 2, wn = wid & 3;
  const int flip = (lo & 7) << 4;  // read-side XOR: byte ^= (row&7)<<4

  // T1: bijective XCD swizzle (grid % 8 == 0 for both modes)
  const int nwg = gridDim.x;
  const int orig = blockIdx.x;
  const int bid = (orig & 7) * (nwg >> 3) + (orig >> 3);

  const int z = (MODE == 0) ? (bid >> 9) : 3;
  const int by = (MODE == 0) ? ((bid & 511) >> 3) : (bid >> 3);
  const int bx = bid & 7;
  const int m0 = by * 256, n0 = bx * 256;
  const unsigned short* const Ag = A;
  const unsigned short* const Bg = WtAll + (size_t)z * DIMS * DIMS;

  f32x4 acc[8][4];
  #pragma unroll
  for (int i = 0; i < 8; ++i)
    #pragma unroll
    for (int j = 0; j < 4; ++j)
      acc[i][j] = (f32x4){0.f, 0.f, 0.f, 0.f};

  // stage one 128-row half-tile (16 KB): linear LDS dest, inverse-swizzled source.
  // LDS dest of lane l in chunk c: row = c*8 + (l>>3), colbyte = (l&7)*16.
  // Source colbyte = ((l&7) ^ (l>>3)) * 16  (row&7 == l>>3).
  auto stage_half = [&](const unsigned short* __restrict__ G, int grow0, int tile,
                        unsigned short* dst) {
    const int k0 = tile * 64;
    #pragma unroll
    for (int h8 = 0; h8 < 2; ++h8) {
      const int c = h8 * 8 + wid;
      const int row = c * 8 + (lane >> 3);
      const int col8 = (lane & 7) ^ (lane >> 3);
      async16(G + (size_t)(grow0 + row) * DIMS + k0 + col8 * 8, dst + c * 512);
    }
  };
  auto rdA = [&](const unsigned short* base, int i, int kk) -> bf16x8 {
    const int r = i * 32 + wm * 16 + lo;
    const int cb = (kk * 64 + hi * 16) ^ flip;
    return *(const bf16x8*)((const char*)base + r * 128 + cb);
  };
  auto rdB = [&](const unsigned short* base, int j, int kk) -> bf16x8 {
    const int r = j * 64 + wn * 16 + lo;
    const int cb = (kk * 64 + hi * 16) ^ flip;
    return *(const bf16x8*)((const char*)base + r * 128 + cb);
  };

  bf16x8 aq[4][2], b0[2][2], b1[2][2];

  // prologue: tile0 full + {A0,B0,B1}(1); vmcnt(6) => tile0 landed, 3 halves in flight
  stage_half(Ag, m0,       0, As0);
  stage_half(Bg, n0,       0, Bs0);
  stage_half(Ag, m0 + 128, 0, As0 + 8192);
  stage_half(Bg, n0 + 128, 0, Bs0 + 8192);
  stage_half(Ag, m0,       1, As1);
  stage_half(Bg, n0,       1, Bs1);
  stage_half(Bg, n0 + 128, 1, Bs1 + 8192);
  WAIT_VM(6);
  BAR();

  #pragma unroll 1
  for (int it = 0; it < 16; ++it) {
    const int t = 2 * it;
    const bool pre = (it < 15);
    // ---- P1: read A0,B0(buf0); stage A1(t+1)->buf1; MFMA (qm0,qn0)
    #pragma unroll
    for (int i = 0; i < 4; ++i) { aq[i][0] = rdA(As0, i, 0); aq[i][1] = rdA(As0, i, 1); }
    #pragma unroll
    for (int j = 0; j < 2; ++j) { b0[j][0] = rdB(Bs0, j, 0); b0[j][1] = rdB(Bs0, j, 1); }
    stage_half(Ag, m0 + 128, t + 1, As1 + 8192);
    BAR(); WAIT_LGKM0();
    __builtin_amdgcn_s_setprio(1);
    #pragma unroll
    for (int kk = 0; kk < 2; ++kk)
      #pragma unroll
      for (int i = 0; i < 4; ++i)
        #pragma unroll
        for (int j = 0; j < 2; ++j)
          acc[i][j] = MFMA16(aq[i][kk], b0[j][kk], acc[i][j]);
    __builtin_amdgcn_s_setprio(0);
    BAR();
    // ---- P2: read B1(buf0); stage A0(t+2)->buf0; MFMA (qm0,qn1)
    #pragma unroll
    for (int j = 0; j < 2; ++j) { b1[j][0] = rdB(Bs0, 2 + j, 0); b1[j][1] = rdB(Bs0, 2 + j, 1); }
    if (pre) stage_half(Ag, m0, t + 2, As0);
    BAR(); WAIT_LGKM0();
    __builtin_amdgcn_s_setprio(1);
    #pragma unroll
    for (int kk = 0; kk < 2; ++kk)
      #pragma unroll
      for (int i = 0; i < 4; ++i)
        #pragma unroll
        for (int j = 0; j < 2; ++j)
          acc[i][2 + j] = MFMA16(aq[i][kk], b1[j][kk], acc[i][2 + j]);
    __builtin_amdgcn_s_setprio(0);
    BAR();
    // ---- P3: read A1(buf0) into aq; stage B0(t+2)->buf0; MFMA (qm1,qn0)
    #pragma unroll
    for (int i = 0; i < 4; ++i) { aq[i][0] = rdA(As0, 4 + i, 0); aq[i][1] = rdA(As0, 4 + i, 1); }
    if (pre) stage_half(Bg, n0, t + 2, Bs0);
    BAR(); WAIT_LGKM0();
    __builtin_amdgcn_s_setprio(1);
    #pragma unroll
    for (int kk = 0; kk < 2; ++kk)
      #pragma unroll
      for (int i = 0; i < 4; ++i)
        #pragma unroll
        for (int j = 0; j < 2; ++j)
          acc[4 + i][j] = MFMA16(aq[i][kk], b0[j][kk], acc[4 + i][j]);
    __builtin_amdgcn_s_setprio(0);
    BAR();
    // ---- P4: stage B1(t+2)->buf0; MFMA (qm1,qn1); counted vmcnt
    if (pre) stage_half(Bg, n0 + 128, t + 2, Bs0 + 8192);
    BAR();
    __builtin_amdgcn_s_setprio(1);
    #pragma unroll
    for (int kk = 0; kk < 2; ++kk)
      #pragma unroll
      for (int i = 0; i < 4; ++i)
        #pragma unroll
        for (int j = 0; j < 2; ++j)
          acc[4 + i][2 + j] = MFMA16(aq[i][kk], b1[j][kk], acc[4 + i][2 + j]);
    __builtin_amdgcn_s_setprio(0);
    if (it == 15) { WAIT_VM(0); } else { WAIT_VM(6); }
    BAR();
    // ---- P5: read A0,B0(buf1); stage A1(t+2)->buf0; MFMA (qm0,qn0) of t+1
    #pragma unroll
    for (int i = 0; i < 4; ++i) { aq[i][0] = rdA(As1, i, 0); aq[i][1] = rdA(As1, i, 1); }
    #pragma unroll
    for (int j = 0; j < 2; ++j) { b0[j][0] = rdB(Bs1, j, 0); b0[j][1] = rdB(Bs1, j, 1); }
    if (pre) stage_half(Ag, m0 + 128, t + 2, As0 + 8192);
    BAR(); WAIT_LGKM0();
    __builtin_amdgcn_s_setprio(1);
    #pragma unroll
    for (int kk = 0; kk < 2; ++kk)
      #pragma unroll
      for (int i = 0; i < 4; ++i)
        #pragma unroll
        for (int j = 0; j < 2; ++j)
          acc[i][j] = MFMA16(aq[i][kk], b0[j][kk], acc[i][j]);
    __builtin_amdgcn_s_setprio(0);
    BAR();
    // ---- P6: read B1(buf1); stage A0(t+3)->buf1; MFMA (qm0,qn1)
    #pragma unroll
    for (int j = 0; j < 2; ++j) { b1[j][0] = rdB(Bs1, 2 + j, 0); b1[j][1] = rdB(Bs1, 2 + j, 1); }
    if (pre) stage_half(Ag, m0, t + 3, As1);
    BAR(); WAIT_LGKM0();
    __builtin_amdgcn_s_setprio(1);
    #pragma unroll
    for (int kk = 0; kk < 2; ++kk)
      #pragma unroll
      for (int i = 0; i < 4; ++i)
        #pragma unroll
        for (int j = 0; j < 2; ++j)
          acc[i][2 + j] = MFMA16(aq[i][kk], b1[j][kk], acc[i][2 + j]);
    __builtin_amdgcn_s_setprio(0);
    BAR();
    // ---- P7: read A1(buf1); stage B0(t+3)->buf1; MFMA (qm1,qn0)
    #pragma unroll
    for (int i = 0; i < 4; ++i) { aq[i][0] = rdA(As1, 4 + i, 0); aq[i][1] = rdA(As1, 4 + i, 1); }
    if (pre) stage_half(Bg, n0, t + 3, Bs1);
    BAR(); WAIT_LGKM0();
    __builtin_amdgcn_s_setprio(1);
    #pragma unroll
    for (int kk = 0; kk < 2; ++kk)
      #pragma unroll
      for (int i = 0; i < 4; ++i)
        #pragma unroll
        for (int j = 0; j < 2; ++j)
          acc[4 + i][j] = MFMA16(aq[i][kk], b0[j][kk], acc[4 + i][j]);
    __builtin_amdgcn_s_setprio(0);
    BAR();
    // ---- P8: stage B1(t+3)->buf1; MFMA (qm1,qn1); counted vmcnt
    if (pre) stage_half(Bg, n0 + 128, t + 3, Bs1 + 8192);
    BAR();
    __builtin_amdgcn_s_setprio(1);
    #pragma unroll
    for (int kk = 0; kk < 2; ++kk)
      #pragma unroll
      for (int i = 0; i < 4; ++i)
        #pragma unroll
        for (int j = 0; j < 2; ++j)
          acc[4 + i][2 + j] = MFMA16(aq[i][kk], b1[j][kk], acc[4 + i][2 + j]);
    __builtin_amdgcn_s_setprio(0);
    WAIT_VM(6);
    BAR();
  }

  // epilogue
  const int rope = (MODE == 0) && (z < 2);
  unsigned short* outb = (MODE == 0) ? (OutB + (size_t)z * MROWS * DIMS) : (unsigned short*)nullptr;
  #pragma unroll
  for (int i = 0; i < 8; ++i) {
    #pragma unroll
    for (int rr = 0; rr < 4; ++rr) {
      const int row = m0 + i * 32 + wm * 16 + hi * 4 + rr;
      const int s = row & (SEQ - 1);
      if (MODE == 1) {
        float* o = OutF + (size_t)row * DIMS + n0;
        #pragma unroll
        for (int j = 0; j < 4; ++j) o[j * 64 + wn * 16 + lo] = acc[i][j][rr];
      } else if (rope) {
        unsigned short* o = outb + (size_t)row * DIMS + n0;
        const int d = wn * 16 + lo;  // < 64
        const float c = cosT[s * 64 + d], sn = sinT[s * 64 + d];
        #pragma unroll
        for (int p = 0; p < 2; ++p) {  // p=0: head n0/128, p=1: head n0/128+1
          const float v1 = acc[i][2 * p][rr], v2 = acc[i][2 * p + 1][rr];
          o[p * 128 + d]      = f2bf(v1 * c - v2 * sn);
          o[p * 128 + d + 64] = f2bf(v2 * c + v1 * sn);
        }
      } else {
        unsigned short* o = outb + (size_t)row * DIMS + n0;
        #pragma unroll
        for (int j = 0; j < 4; ++j) o[j * 64 + wn * 16 + lo] = f2bf(acc[i][j][rr]);
      }
    }
  }
}

// ---------------- block sliding-window attention ----------------
// grid: B*C*H = 1024 blocks; block = 512 threads = 8 waves; wave = 32 q-rows.
__global__ __launch_bounds__(512) void attn(
    const unsigned short* __restrict__ Qb,
    const unsigned short* __restrict__ Kb,
    const unsigned short* __restrict__ Vb,
    unsigned short* __restrict__ AO) {
  __shared__ unsigned short Ksm[64 * 136];      // [64 keys][128 d + 8 pad]
  __shared__ unsigned short Vsm[128 * 72];      // V^T: [128 d][64 keys + 8 pad]
  __shared__ unsigned short Psm[8 * 32 * 72];   // per wave [32 q][64 keys + 8 pad]

  const int bid = blockIdx.x;
  const int h = bid & 15;
  const int c = (bid >> 4) & 31;
  const int b = bid >> 9;
  const int tid = threadIdx.x;
  const int wid = tid >> 6, lane = tid & 63;
  const int lo = lane & 15, hi = lane >> 4;
  const float SCALE = 0.08838834764831845f;  // 1/sqrt(128)

  // hoist Q fragments into registers
  bf16x8 qf[2][4];
  {
    const size_t base = ((size_t)(b * SEQ + c * WINW + wid * 32 + lo)) * DIMS + h * HD;
    #pragma unroll
    for (int m = 0; m < 2; ++m)
      #pragma unroll
      for (int ks = 0; ks < 4; ++ks)
        qf[m][ks] = *(const bf16x8*)&Qb[base + (size_t)m * 16 * DIMS + ks * 32 + hi * 8];
  }

  f32x4 O[2][8];
  float mrow[2][4], lrow[2][4];
  #pragma unroll
  for (int m = 0; m < 2; ++m) {
    #pragma unroll
    for (int n = 0; n < 8; ++n) O[m][n] = (f32x4){0.f, 0.f, 0.f, 0.f};
    #pragma unroll
    for (int r = 0; r < 4; ++r) { mrow[m][r] = -INFINITY; lrow[m][r] = 0.f; }
  }

  unsigned short* Pw = Psm + wid * 32 * 72;
  const int t0 = (c == 0) ? 4 : 0;  // block-uniform: skip prev-chunk tiles for chunk 0

  for (int t = t0; t < 8; ++t) {
    const int krow_base = b * SEQ + (c - 1) * WINW + t * 64;  // absolute seq row of tile key 0
    // stage K [64][128] (vector) and V transposed [128][64]
    #pragma unroll
    for (int i = 0; i < 2; ++i) {
      const int cid = i * 512 + tid;
      const int kr = cid >> 4;
      const int d8 = (cid & 15) << 3;
      *(bf16x8*)&Ksm[kr * 136 + d8] =
          *(const bf16x8*)&Kb[(size_t)(krow_base + kr) * DIMS + h * HD + d8];
      bf16x8 v = *(const bf16x8*)&Vb[(size_t)(krow_base + kr) * DIMS + h * HD + d8];
      #pragma unroll
      for (int e = 0; e < 8; ++e)
        Vsm[(d8 + e) * 72 + kr] = (unsigned short)v[e];
    }
    __syncthreads();

    // S = Q @ K^T  (64 keys)
    f32x4 S[2][4];
    #pragma unroll
    for (int m = 0; m < 2; ++m)
      #pragma unroll
      for (int n = 0; n < 4; ++n)
        S[m][n] = (f32x4){0.f, 0.f, 0.f, 0.f};
    #pragma unroll
    for (int ks = 0; ks < 4; ++ks) {
      const int ko = ks * 32 + hi * 8;
      bf16x8 kf[4];
      #pragma unroll
      for (int n = 0; n < 4; ++n)
        kf[n] = *(const bf16x8*)&Ksm[(n * 16 + lo) * 136 + ko];
      #pragma unroll
      for (int m = 0; m < 2; ++m)
        #pragma unroll
        for (int n = 0; n < 4; ++n)
          S[m][n] = __builtin_amdgcn_mfma_f32_16x16x32_bf16(qf[m][ks], kf[n], S[m][n], 0, 0, 0);
    }

    // mask + online softmax
    #pragma unroll
    for (int m = 0; m < 2; ++m) {
      #pragma unroll
      for (int r = 0; r < 4; ++r) {
        const int qrow = wid * 32 + m * 16 + hi * 4 + r;
        float tmax = -INFINITY;
        #pragma unroll
        for (int n = 0; n < 4; ++n) {
          const int kc = t * 64 + n * 16 + lo;
          float v = S[m][n][r] * SCALE;
          const bool ok = (kc < WINW) ? (c > 0) : ((kc - WINW) <= qrow);
          v = ok ? v : -INFINITY;
          S[m][n][r] = v;
          tmax = fmaxf(tmax, v);
        }
        tmax = fmaxf(tmax, __shfl_xor(tmax, 1));
        tmax = fmaxf(tmax, __shfl_xor(tmax, 2));
        tmax = fmaxf(tmax, __shfl_xor(tmax, 4));
        tmax = fmaxf(tmax, __shfl_xor(tmax, 8));
        const float mold = mrow[m][r];
        const float mnew = fmaxf(mold, tmax);
        const float corr = __expf(mold - mnew);
        float rsum = 0.f;
        #pragma unroll
        for (int n = 0; n < 4; ++n) {
          const float p = __expf(S[m][n][r] - mnew);
          S[m][n][r] = p;
          rsum += p;
        }
        rsum += __shfl_xor(rsum, 1);
        rsum += __shfl_xor(rsum, 2);
        rsum += __shfl_xor(rsum, 4);
        rsum += __shfl_xor(rsum, 8);
        mrow[m][r] = mnew;
        lrow[m][r] = lrow[m][r] * corr + rsum;
        #pragma unroll
        for (int n = 0; n < 8; ++n) O[m][n][r] *= corr;
        #pragma unroll
        for (int n = 0; n < 4; ++n)
          Pw[(m * 16 + hi * 4 + r) * 72 + n * 16 + lo] = f2bf(S[m][n][r]);
      }
    }
    asm volatile("" ::: "memory");  // keep P stores before P reads (DS is in-order per wave)

    // O += P @ V
    #pragma unroll
    for (int kk = 0; kk < 2; ++kk) {
      const int ko = kk * 32 + hi * 8;
      bf16x8 pf[2], vf[8];
      #pragma unroll
      for (int m = 0; m < 2; ++m)
        pf[m] = *(const bf16x8*)&Pw[(m * 16 + lo) * 72 + ko];
      #pragma unroll
      for (int n = 0; n < 8; ++n)
        vf[n] = *(const bf16x8*)&Vsm[(n * 16 + lo) * 72 + ko];
      #pragma unroll
      for (int m = 0; m < 2; ++m)
        #pragma unroll
        for (int n = 0; n < 8; ++n)
          O[m][n] = __builtin_amdgcn_mfma_f32_16x16x32_bf16(pf[m], vf[n], O[m][n], 0, 0, 0);
    }
    __syncthreads();
  }

  // normalize + write bf16 attention output [B,S,H*D]
  #pragma unroll
  for (int m = 0; m < 2; ++m) {
    #pragma unroll
    for (int r = 0; r < 4; ++r) {
      const float inv = 1.f / lrow[m][r];
      const size_t row = (size_t)(b * SEQ + c * WINW + wid * 32 + m * 16 + hi * 4 + r);
      unsigned short* o = AO + row * DIMS + h * HD;
      #pragma unroll
      for (int n = 0; n < 8; ++n)
        o[n * 16 + lo] = f2bf(O[m][n][r] * inv);
    }
  }
}

extern "C" void kernel_launch(void* const* d_in, const int* in_sizes, int n_in,
                              void* d_out, int out_size, void* d_ws, size_t ws_size,
                              hipStream_t stream) {
  const float* H  = (const float*)d_in[0];
  const float* Wq = (const float*)d_in[1];
  const float* Wk = (const float*)d_in[2];
  const float* Wv = (const float*)d_in[3];
  const float* Wo = (const float*)d_in[4];
  float* out = (float*)d_out;

  // workspace layout (373.3 MB total)
  unsigned short* Wt  = (unsigned short*)d_ws;                  // 4*2048*2048 bf16
  unsigned short* Hb  = Wt + (size_t)4 * DIMS * DIMS;           // 16384*2048 bf16
  unsigned short* QKV = Hb + (size_t)MROWS * DIMS;              // 3 x 16384*2048 bf16
  unsigned short* AO  = QKV + (size_t)3 * MROWS * DIMS;         // 16384*2048 bf16
  float* cosT = (float*)(AO + (size_t)MROWS * DIMS);            // 8192*64 f32
  float* sinT = cosT + (size_t)SEQ * 64;

  wconv<<<dim3(32, 32, 4), 256, 0, stream>>>(Wq, Wk, Wv, Wo, Wt);
  hconv<<<2048, 256, 0, stream>>>(H, Hb);
  rope_tab<<<2048, 256, 0, stream>>>(cosT, sinT);
  gemm256<0><<<1536, 512, 0, stream>>>(Hb, Wt, QKV, nullptr, cosT, sinT);
  attn<<<dim3(1024), 512, 0, stream>>>(QKV, QKV + (size_t)MROWS * DIMS,
                                       QKV + (size_t)2 * MROWS * DIMS, AO);
  gemm256<1><<<512, 512, 0, stream>>>(AO, Wt, nullptr, out, cosT, sinT);
}

// Round 4
// 739.598 us; speedup vs baseline: 1.5225x; 1.1046x over previous
//
#include <hip/hip_runtime.h>
#include <cmath>

#define DIMS 2048
#define SEQ  8192
#define NB   2
#define HEADS 16
#define HD   128
#define WINW 256
#define MROWS 16384  // NB*SEQ
#define NCH  32      // SEQ/WINW

using bf16x8 = __attribute__((ext_vector_type(8))) short;
using f32x4  = __attribute__((ext_vector_type(4))) float;

__device__ __forceinline__ unsigned short f2bf(float f) {
  unsigned int u = __float_as_uint(f);
  u += 0x7FFF + ((u >> 16) & 1);
  return (unsigned short)(u >> 16);
}

__device__ __forceinline__ void async16(const unsigned short* g, unsigned short* l) {
  __builtin_amdgcn_global_load_lds((const __attribute__((address_space(1))) void*)g,
                                   (__attribute__((address_space(3))) void*)l,
                                   16, 0, 0);
}

#define BAR() __builtin_amdgcn_s_barrier()
#define WAIT_LGKM0() do { asm volatile("s_waitcnt lgkmcnt(0)" ::: "memory"); \
                          __builtin_amdgcn_sched_barrier(0); } while (0)
#define WAIT_VM(n) asm volatile("s_waitcnt vmcnt(" #n ")" ::: "memory")
#define MFMA16(a, b, c) __builtin_amdgcn_mfma_f32_16x16x32_bf16(a, b, c, 0, 0, 0)

// ---------------- weight transpose+convert: W[K,N] f32 -> Wt[N,K] bf16 ----------------
__global__ void wconv(const float* __restrict__ w0, const float* __restrict__ w1,
                      const float* __restrict__ w2, const float* __restrict__ w3,
                      unsigned short* __restrict__ Wt) {
  __shared__ unsigned short tile[64][65];
  const float* W = (blockIdx.z == 0) ? w0 : (blockIdx.z == 1) ? w1 : (blockIdx.z == 2) ? w2 : w3;
  unsigned short* O = Wt + (size_t)blockIdx.z * DIMS * DIMS;
  const int k0 = blockIdx.y * 64, n0 = blockIdx.x * 64;
  const int t = threadIdx.x;
  #pragma unroll
  for (int p = 0; p < 16; ++p) {
    int i = p * 4 + (t >> 6);
    int j = t & 63;
    tile[i][j] = f2bf(W[(size_t)(k0 + i) * DIMS + n0 + j]);
  }
  __syncthreads();
  #pragma unroll
  for (int p = 0; p < 16; ++p) {
    int a = p * 4 + (t >> 6);
    int b = t & 63;
    O[(size_t)(n0 + a) * DIMS + k0 + b] = tile[b][a];
  }
}

// ---------------- hidden f32 -> bf16 ----------------
__global__ void hconv(const float* __restrict__ in, unsigned short* __restrict__ outp) {
  const long n4 = (long)MROWS * DIMS / 4;
  long i = (long)blockIdx.x * blockDim.x + threadIdx.x;
  const long stride = (long)gridDim.x * blockDim.x;
  for (; i < n4; i += stride) {
    float4 v = ((const float4*)in)[i];
    ushort4 o;
    o.x = f2bf(v.x); o.y = f2bf(v.y); o.z = f2bf(v.z); o.w = f2bf(v.w);
    ((ushort4*)outp)[i] = o;
  }
}

// ---------------- RoPE table: [8192][64] cos/sin ----------------
__global__ void rope_tab(float* __restrict__ cosT, float* __restrict__ sinT) {
  int t = blockIdx.x * 256 + threadIdx.x;  // 524288 total
  int pos = t >> 6, i = t & 63;
  double inv = pow(10000.0, -(double)i / 64.0);
  double ang = (double)pos * inv;
  cosT[t] = (float)cos(ang);
  sinT[t] = (float)sin(ang);
}

// ---------------- 256x256 8-phase GEMM: A[M,K]bf16 @ Bt[N,K]^T ----------------
// 512 thr = 8 waves (2M x 4N), BK=64, LDS 128KB double-buffered.
// LDS swizzle: byte ^= (row&7)<<4 (read side); inverse-swizzled global source,
// linear global_load_lds dest (rule 21). Conflict-free (verified: R3 conflicts=0).
// MODE 0: QKV, by-major (by,z,bx) mapping; z<2 RoPE bf16 out; z==2 writes V
//         TRANSPOSED to Vt[b,h,d,s] (ushort4 over 4 consecutive-row acc elems).
// MODE 1: O-proj (f32 out to d_out).
template<int MODE>
__global__ __launch_bounds__(512, 2) void gemm256(
    const unsigned short* __restrict__ A,
    const unsigned short* __restrict__ WtAll,
    unsigned short* __restrict__ OutB,
    float* __restrict__ OutF,
    const float* __restrict__ cosT,
    const float* __restrict__ sinT) {
  __shared__ __align__(1024) unsigned short lds[65536];  // 128 KiB
  unsigned short* const As0 = lds;           // buf0 A [256][64]
  unsigned short* const Bs0 = lds + 16384;   // buf0 B
  unsigned short* const As1 = lds + 32768;   // buf1 A
  unsigned short* const Bs1 = lds + 49152;   // buf1 B

  const int tid = threadIdx.x;
  const int wid = tid >> 6, lane = tid & 63;
  const int lo = lane & 15, hi = lane >> 4;
  const int wm = wid >> 2, wn = wid & 3;
  const int flip = (lo & 7) << 4;  // read-side XOR: byte ^= (row&7)<<4

  // T1: bijective XCD swizzle (grid % 8 == 0 for both modes)
  const int nwg = gridDim.x;
  const int orig = blockIdx.x;
  const int bid = (orig & 7) * (nwg >> 3) + (orig >> 3);

  // by-major mapping: consecutive bids share the A-panel (L2 locality per XCD)
  int by, bx, z;
  if (MODE == 0) {
    by = bid / 24;
    const int rem = bid - by * 24;
    z = rem >> 3;
    bx = rem & 7;
  } else {
    by = bid >> 3; bx = bid & 7; z = 3;
  }
  const int m0 = by * 256, n0 = bx * 256;
  const unsigned short* const Ag = A;
  const unsigned short* const Bg = WtAll + (size_t)z * DIMS * DIMS;

  f32x4 acc[8][4];
  #pragma unroll
  for (int i = 0; i < 8; ++i)
    #pragma unroll
    for (int j = 0; j < 4; ++j)
      acc[i][j] = (f32x4){0.f, 0.f, 0.f, 0.f};

  // stage one 128-row half-tile (16 KB): linear LDS dest, inverse-swizzled source.
  auto stage_half = [&](const unsigned short* __restrict__ G, int grow0, int tile,
                        unsigned short* dst) {
    const int k0 = tile * 64;
    #pragma unroll
    for (int h8 = 0; h8 < 2; ++h8) {
      const int c = h8 * 8 + wid;
      const int row = c * 8 + (lane >> 3);
      const int col8 = (lane & 7) ^ (lane >> 3);
      async16(G + (size_t)(grow0 + row) * DIMS + k0 + col8 * 8, dst + c * 512);
    }
  };
  auto rdA = [&](const unsigned short* base, int i, int kk) -> bf16x8 {
    const int r = i * 32 + wm * 16 + lo;
    const int cb = (kk * 64 + hi * 16) ^ flip;
    return *(const bf16x8*)((const char*)base + r * 128 + cb);
  };
  auto rdB = [&](const unsigned short* base, int j, int kk) -> bf16x8 {
    const int r = j * 64 + wn * 16 + lo;
    const int cb = (kk * 64 + hi * 16) ^ flip;
    return *(const bf16x8*)((const char*)base + r * 128 + cb);
  };

  bf16x8 aq[4][2], b0[2][2], b1[2][2];

  // prologue: tile0 full + {A0,B0,B1}(1); vmcnt(6) => tile0 landed, 3 halves in flight
  stage_half(Ag, m0,       0, As0);
  stage_half(Bg, n0,       0, Bs0);
  stage_half(Ag, m0 + 128, 0, As0 + 8192);
  stage_half(Bg, n0 + 128, 0, Bs0 + 8192);
  stage_half(Ag, m0,       1, As1);
  stage_half(Bg, n0,       1, Bs1);
  stage_half(Bg, n0 + 128, 1, Bs1 + 8192);
  WAIT_VM(6);
  BAR();

  #pragma unroll 1
  for (int it = 0; it < 16; ++it) {
    const int t = 2 * it;
    const bool pre = (it < 15);
    // ---- P1: read A0,B0(buf0); stage A1(t+1)->buf1; MFMA (qm0,qn0)
    #pragma unroll
    for (int i = 0; i < 4; ++i) { aq[i][0] = rdA(As0, i, 0); aq[i][1] = rdA(As0, i, 1); }
    #pragma unroll
    for (int j = 0; j < 2; ++j) { b0[j][0] = rdB(Bs0, j, 0); b0[j][1] = rdB(Bs0, j, 1); }
    stage_half(Ag, m0 + 128, t + 1, As1 + 8192);
    BAR(); WAIT_LGKM0();
    __builtin_amdgcn_s_setprio(1);
    #pragma unroll
    for (int kk = 0; kk < 2; ++kk)
      #pragma unroll
      for (int i = 0; i < 4; ++i)
        #pragma unroll
        for (int j = 0; j < 2; ++j)
          acc[i][j] = MFMA16(aq[i][kk], b0[j][kk], acc[i][j]);
    __builtin_amdgcn_s_setprio(0);
    BAR();
    // ---- P2: read B1(buf0); stage A0(t+2)->buf0; MFMA (qm0,qn1)
    #pragma unroll
    for (int j = 0; j < 2; ++j) { b1[j][0] = rdB(Bs0, 2 + j, 0); b1[j][1] = rdB(Bs0, 2 + j, 1); }
    if (pre) stage_half(Ag, m0, t + 2, As0);
    BAR(); WAIT_LGKM0();
    __builtin_amdgcn_s_setprio(1);
    #pragma unroll
    for (int kk = 0; kk < 2; ++kk)
      #pragma unroll
      for (int i = 0; i < 4; ++i)
        #pragma unroll
        for (int j = 0; j < 2; ++j)
          acc[i][2 + j] = MFMA16(aq[i][kk], b1[j][kk], acc[i][2 + j]);
    __builtin_amdgcn_s_setprio(0);
    BAR();
    // ---- P3: read A1(buf0) into aq; stage B0(t+2)->buf0; MFMA (qm1,qn0)
    #pragma unroll
    for (int i = 0; i < 4; ++i) { aq[i][0] = rdA(As0, 4 + i, 0); aq[i][1] = rdA(As0, 4 + i, 1); }
    if (pre) stage_half(Bg, n0, t + 2, Bs0);
    BAR(); WAIT_LGKM0();
    __builtin_amdgcn_s_setprio(1);
    #pragma unroll
    for (int kk = 0; kk < 2; ++kk)
      #pragma unroll
      for (int i = 0; i < 4; ++i)
        #pragma unroll
        for (int j = 0; j < 2; ++j)
          acc[4 + i][j] = MFMA16(aq[i][kk], b0[j][kk], acc[4 + i][j]);
    __builtin_amdgcn_s_setprio(0);
    BAR();
    // ---- P4: stage B1(t+2)->buf0; MFMA (qm1,qn1); counted vmcnt
    if (pre) stage_half(Bg, n0 + 128, t + 2, Bs0 + 8192);
    BAR();
    __builtin_amdgcn_s_setprio(1);
    #pragma unroll
    for (int kk = 0; kk < 2; ++kk)
      #pragma unroll
      for (int i = 0; i < 4; ++i)
        #pragma unroll
        for (int j = 0; j < 2; ++j)
          acc[4 + i][2 + j] = MFMA16(aq[i][kk], b1[j][kk], acc[4 + i][2 + j]);
    __builtin_amdgcn_s_setprio(0);
    if (it == 15) { WAIT_VM(0); } else { WAIT_VM(6); }
    BAR();
    // ---- P5: read A0,B0(buf1); stage A1(t+2)->buf0; MFMA (qm0,qn0) of t+1
    #pragma unroll
    for (int i = 0; i < 4; ++i) { aq[i][0] = rdA(As1, i, 0); aq[i][1] = rdA(As1, i, 1); }
    #pragma unroll
    for (int j = 0; j < 2; ++j) { b0[j][0] = rdB(Bs1, j, 0); b0[j][1] = rdB(Bs1, j, 1); }
    if (pre) stage_half(Ag, m0 + 128, t + 2, As0 + 8192);
    BAR(); WAIT_LGKM0();
    __builtin_amdgcn_s_setprio(1);
    #pragma unroll
    for (int kk = 0; kk < 2; ++kk)
      #pragma unroll
      for (int i = 0; i < 4; ++i)
        #pragma unroll
        for (int j = 0; j < 2; ++j)
          acc[i][j] = MFMA16(aq[i][kk], b0[j][kk], acc[i][j]);
    __builtin_amdgcn_s_setprio(0);
    BAR();
    // ---- P6: read B1(buf1); stage A0(t+3)->buf1; MFMA (qm0,qn1)
    #pragma unroll
    for (int j = 0; j < 2; ++j) { b1[j][0] = rdB(Bs1, 2 + j, 0); b1[j][1] = rdB(Bs1, 2 + j, 1); }
    if (pre) stage_half(Ag, m0, t + 3, As1);
    BAR(); WAIT_LGKM0();
    __builtin_amdgcn_s_setprio(1);
    #pragma unroll
    for (int kk = 0; kk < 2; ++kk)
      #pragma unroll
      for (int i = 0; i < 4; ++i)
        #pragma unroll
        for (int j = 0; j < 2; ++j)
          acc[i][2 + j] = MFMA16(aq[i][kk], b1[j][kk], acc[i][2 + j]);
    __builtin_amdgcn_s_setprio(0);
    BAR();
    // ---- P7: read A1(buf1); stage B0(t+3)->buf1; MFMA (qm1,qn0)
    #pragma unroll
    for (int i = 0; i < 4; ++i) { aq[i][0] = rdA(As1, 4 + i, 0); aq[i][1] = rdA(As1, 4 + i, 1); }
    if (pre) stage_half(Bg, n0, t + 3, Bs1);
    BAR(); WAIT_LGKM0();
    __builtin_amdgcn_s_setprio(1);
    #pragma unroll
    for (int kk = 0; kk < 2; ++kk)
      #pragma unroll
      for (int i = 0; i < 4; ++i)
        #pragma unroll
        for (int j = 0; j < 2; ++j)
          acc[4 + i][j] = MFMA16(aq[i][kk], b0[j][kk], acc[4 + i][j]);
    __builtin_amdgcn_s_setprio(0);
    BAR();
    // ---- P8: stage B1(t+3)->buf1; MFMA (qm1,qn1); counted vmcnt
    if (pre) stage_half(Bg, n0 + 128, t + 3, Bs1 + 8192);
    BAR();
    __builtin_amdgcn_s_setprio(1);
    #pragma unroll
    for (int kk = 0; kk < 2; ++kk)
      #pragma unroll
      for (int i = 0; i < 4; ++i)
        #pragma unroll
        for (int j = 0; j < 2; ++j)
          acc[4 + i][2 + j] = MFMA16(aq[i][kk], b1[j][kk], acc[4 + i][2 + j]);
    __builtin_amdgcn_s_setprio(0);
    WAIT_VM(6);
    BAR();
  }

  // epilogue
  if (MODE == 0 && z == 2) {
    // V transposed: Vt[b, h, d, s] with layout ((b*2048 + col) << 13) + s
    unsigned short* vt = OutB + (size_t)2 * MROWS * DIMS;
    #pragma unroll
    for (int i = 0; i < 8; ++i) {
      const int row0 = m0 + i * 32 + wm * 16 + hi * 4;
      const int bb = row0 >> 13;
      const int s0 = row0 & (SEQ - 1);
      #pragma unroll
      for (int j = 0; j < 4; ++j) {
        const int colg = n0 + j * 64 + wn * 16 + lo;
        ushort4 pk;
        pk.x = f2bf(acc[i][j][0]); pk.y = f2bf(acc[i][j][1]);
        pk.z = f2bf(acc[i][j][2]); pk.w = f2bf(acc[i][j][3]);
        *(ushort4*)&vt[(((size_t)(bb * 2048 + colg)) << 13) + s0] = pk;
      }
    }
  } else {
    unsigned short* outb = (MODE == 0) ? (OutB + (size_t)z * MROWS * DIMS)
                                       : (unsigned short*)nullptr;
    #pragma unroll
    for (int i = 0; i < 8; ++i) {
      #pragma unroll
      for (int rr = 0; rr < 4; ++rr) {
        const int row = m0 + i * 32 + wm * 16 + hi * 4 + rr;
        const int s = row & (SEQ - 1);
        if (MODE == 1) {
          float* o = OutF + (size_t)row * DIMS + n0;
          #pragma unroll
          for (int j = 0; j < 4; ++j) o[j * 64 + wn * 16 + lo] = acc[i][j][rr];
        } else {  // z < 2: RoPE
          unsigned short* o = outb + (size_t)row * DIMS + n0;
          const int d = wn * 16 + lo;  // < 64
          const float cc = cosT[s * 64 + d], sn = sinT[s * 64 + d];
          #pragma unroll
          for (int p = 0; p < 2; ++p) {
            const float v1 = acc[i][2 * p][rr], v2 = acc[i][2 * p + 1][rr];
            o[p * 128 + d]      = f2bf(v1 * cc - v2 * sn);
            o[p * 128 + d + 64] = f2bf(v2 * cc + v1 * sn);
          }
        }
      }
    }
  }
}

// ---------------- block sliding-window attention ----------------
// grid: B*C*H = 1024 blocks; block = 512 threads = 8 waves; wave = 32 q-rows.
// K staged [64 keys][128 d], V staged [128 d][64 keys] from pre-transposed Vt;
// both via global_load_lds, double-buffered (counted vmcnt), 16B-chunk XOR swizzle.
__global__ __launch_bounds__(512) void attn(
    const unsigned short* __restrict__ Qb,
    const unsigned short* __restrict__ Kb,
    const unsigned short* __restrict__ Vt,
    unsigned short* __restrict__ AO) {
  __shared__ unsigned short Ksm[2][64 * 128];
  __shared__ unsigned short Vsm[2][128 * 64];
  __shared__ unsigned short Psm[8 * 32 * 72];  // per wave [32 q][64 k + 8 pad]

  const int bid = blockIdx.x;
  const int h = bid & 15;
  const int c = (bid >> 4) & 31;
  const int b = bid >> 9;
  const int tid = threadIdx.x;
  const int wid = tid >> 6, lane = tid & 63;
  const int lo = lane & 15, hi = lane >> 4;
  const float SCALE = 0.08838834764831845f;  // 1/sqrt(128)

  // hoist Q fragments into registers
  bf16x8 qf[2][4];
  {
    const size_t base = ((size_t)(b * SEQ + c * WINW + wid * 32 + lo)) * DIMS + h * HD;
    #pragma unroll
    for (int m = 0; m < 2; ++m)
      #pragma unroll
      for (int ks = 0; ks < 4; ++ks)
        qf[m][ks] = *(const bf16x8*)&Qb[base + (size_t)m * 16 * DIMS + ks * 32 + hi * 8];
  }

  f32x4 O[2][8];
  float mrow[2][4], lrow[2][4];
  #pragma unroll
  for (int m = 0; m < 2; ++m) {
    #pragma unroll
    for (int n = 0; n < 8; ++n) O[m][n] = (f32x4){0.f, 0.f, 0.f, 0.f};
    #pragma unroll
    for (int r = 0; r < 4; ++r) { mrow[m][r] = -INFINITY; lrow[m][r] = 0.f; }
  }

  unsigned short* Pw = Psm + wid * 32 * 72;
  const int t0 = (c == 0) ? 4 : 0;  // block-uniform: chunk 0 has no previous chunk

  const unsigned short* Kg0 = Kb + ((size_t)(b * SEQ + (c - 1) * WINW)) * DIMS + h * HD;
  const unsigned short* Vg0 = Vt + (((size_t)(b * 2048 + h * HD)) << 13) + (c - 1) * WINW;

  auto stageKV = [&](int t, int pb) {
    #pragma unroll
    for (int p = 0; p < 2; ++p) {  // K: 64 rows x 16 chunks of 16B
      const int cid = p * 512 + tid;
      const int row = cid >> 4, c16 = cid & 15;
      async16(Kg0 + (size_t)(t * 64 + row) * DIMS + ((c16 ^ (row & 7)) << 3),
              &Ksm[pb][cid * 8]);
    }
    #pragma unroll
    for (int p = 0; p < 2; ++p) {  // V^T: 128 d-rows x 8 chunks of 16B
      const int cid = p * 512 + tid;
      const int rd = cid >> 3, c8 = cid & 7;
      async16(Vg0 + ((size_t)rd << 13) + t * 64 + ((c8 ^ (rd & 7)) << 3),
              &Vsm[pb][cid * 8]);
    }
  };

  stageKV(t0, t0 & 1);
  for (int t = t0; t < 8; ++t) {
    const int pb = t & 1;
    if (t < 7) { stageKV(t + 1, pb ^ 1); WAIT_VM(4); } else { WAIT_VM(0); }
    BAR();

    // S = Q @ K^T  (64 keys)
    f32x4 S[2][4];
    #pragma unroll
    for (int m = 0; m < 2; ++m)
      #pragma unroll
      for (int n = 0; n < 4; ++n)
        S[m][n] = (f32x4){0.f, 0.f, 0.f, 0.f};
    const char* Kbase = (const char*)&Ksm[pb][0];
    #pragma unroll
    for (int ks = 0; ks < 4; ++ks) {
      bf16x8 kf[4];
      #pragma unroll
      for (int n = 0; n < 4; ++n)
        kf[n] = *(const bf16x8*)(Kbase + (n * 16 + lo) * 256 +
                                 (((ks * 4 + hi) ^ (lo & 7)) << 4));
      #pragma unroll
      for (int m = 0; m < 2; ++m)
        #pragma unroll
        for (int n = 0; n < 4; ++n)
          S[m][n] = MFMA16(qf[m][ks], kf[n], S[m][n]);
    }

    // mask + per-row tile max
    float tmax[2][4];
    #pragma unroll
    for (int m = 0; m < 2; ++m) {
      #pragma unroll
      for (int r = 0; r < 4; ++r) {
        const int qrow = wid * 32 + m * 16 + hi * 4 + r;
        float tm = -INFINITY;
        #pragma unroll
        for (int n = 0; n < 4; ++n) {
          const int kc = t * 64 + n * 16 + lo;
          float v = S[m][n][r] * SCALE;
          const bool ok = (kc < WINW) ? (c > 0) : ((kc - WINW) <= qrow);
          v = ok ? v : -INFINITY;
          S[m][n][r] = v;
          tm = fmaxf(tm, v);
        }
        tm = fmaxf(tm, __shfl_xor(tm, 1));
        tm = fmaxf(tm, __shfl_xor(tm, 2));
        tm = fmaxf(tm, __shfl_xor(tm, 4));
        tm = fmaxf(tm, __shfl_xor(tm, 8));
        tmax[m][r] = tm;
      }
    }
    // T13 defer-max: skip rescale when all rows drift <= 8
    float need = -INFINITY;
    #pragma unroll
    for (int m = 0; m < 2; ++m)
      #pragma unroll
      for (int r = 0; r < 4; ++r)
        need = fmaxf(need, tmax[m][r] - mrow[m][r]);
    const bool fast = __all(need <= 8.0f);

    #pragma unroll
    for (int m = 0; m < 2; ++m) {
      #pragma unroll
      for (int r = 0; r < 4; ++r) {
        float mused = mrow[m][r];
        if (!fast) {
          mused = fmaxf(mused, tmax[m][r]);
          const float corr = __expf(mrow[m][r] - mused);
          lrow[m][r] *= corr;
          #pragma unroll
          for (int n = 0; n < 8; ++n) O[m][n][r] *= corr;
          mrow[m][r] = mused;
        }
        float rsum = 0.f;
        #pragma unroll
        for (int n = 0; n < 4; ++n) {
          const float p = __expf(S[m][n][r] - mused);
          S[m][n][r] = p;
          rsum += p;
        }
        rsum += __shfl_xor(rsum, 1);
        rsum += __shfl_xor(rsum, 2);
        rsum += __shfl_xor(rsum, 4);
        rsum += __shfl_xor(rsum, 8);
        lrow[m][r] += rsum;
        #pragma unroll
        for (int n = 0; n < 4; ++n)
          Pw[(m * 16 + hi * 4 + r) * 72 + n * 16 + lo] = f2bf(S[m][n][r]);
      }
    }
    asm volatile("" ::: "memory");  // keep P stores before P reads (DS in-order per wave)

    // O += P @ V
    const char* Vbase = (const char*)&Vsm[pb][0];
    #pragma unroll
    for (int kk = 0; kk < 2; ++kk) {
      const int ko = kk * 32 + hi * 8;
      bf16x8 pf[2], vf[8];
      #pragma unroll
      for (int m = 0; m < 2; ++m)
        pf[m] = *(const bf16x8*)&Pw[(m * 16 + lo) * 72 + ko];
      #pragma unroll
      for (int n = 0; n < 8; ++n)
        vf[n] = *(const bf16x8*)(Vbase + (n * 16 + lo) * 128 +
                                 (((kk * 4 + hi) ^ (lo & 7)) << 4));
      #pragma unroll
      for (int m = 0; m < 2; ++m)
        #pragma unroll
        for (int n = 0; n < 8; ++n)
          O[m][n] = MFMA16(pf[m], vf[n], O[m][n]);
    }
    BAR();
  }

  // normalize + write bf16 attention output [B,S,H*D]
  #pragma unroll
  for (int m = 0; m < 2; ++m) {
    #pragma unroll
    for (int r = 0; r < 4; ++r) {
      const float inv = 1.f / lrow[m][r];
      const size_t row = (size_t)(b * SEQ + c * WINW + wid * 32 + m * 16 + hi * 4 + r);
      unsigned short* o = AO + row * DIMS + h * HD;
      #pragma unroll
      for (int n = 0; n < 8; ++n)
        o[n * 16 + lo] = f2bf(O[m][n][r] * inv);
    }
  }
}

extern "C" void kernel_launch(void* const* d_in, const int* in_sizes, int n_in,
                              void* d_out, int out_size, void* d_ws, size_t ws_size,
                              hipStream_t stream) {
  const float* H  = (const float*)d_in[0];
  const float* Wq = (const float*)d_in[1];
  const float* Wk = (const float*)d_in[2];
  const float* Wv = (const float*)d_in[3];
  const float* Wo = (const float*)d_in[4];
  float* out = (float*)d_out;

  // workspace layout (373.3 MB total)
  unsigned short* Wt  = (unsigned short*)d_ws;                  // 4*2048*2048 bf16
  unsigned short* Hb  = Wt + (size_t)4 * DIMS * DIMS;           // 16384*2048 bf16
  unsigned short* QKV = Hb + (size_t)MROWS * DIMS;              // 3 x 16384*2048 bf16 (z=2 = Vt)
  unsigned short* AO  = QKV + (size_t)3 * MROWS * DIMS;         // 16384*2048 bf16
  float* cosT = (float*)(AO + (size_t)MROWS * DIMS);            // 8192*64 f32
  float* sinT = cosT + (size_t)SEQ * 64;

  wconv<<<dim3(32, 32, 4), 256, 0, stream>>>(Wq, Wk, Wv, Wo, Wt);
  hconv<<<2048, 256, 0, stream>>>(H, Hb);
  rope_tab<<<2048, 256, 0, stream>>>(cosT, sinT);
  gemm256<0><<<1536, 512, 0, stream>>>(Hb, Wt, QKV, nullptr, cosT, sinT);
  attn<<<dim3(1024), 512, 0, stream>>>(QKV, QKV + (size_t)MROWS * DIMS,
                                       QKV + (size_t)2 * MROWS * DIMS, AO);
  gemm256<1><<<512, 512, 0, stream>>>(AO, Wt, nullptr, out, cosT, sinT);
}

// Round 5
// 714.642 us; speedup vs baseline: 1.5757x; 1.0349x over previous
//
#include <hip/hip_runtime.h>
#include <cmath>

#define DIMS 2048
#define SEQ  8192
#define NB   2
#define HEADS 16
#define HD   128
#define WINW 256
#define MROWS 16384  // NB*SEQ
#define NCH  32      // SEQ/WINW

using bf16x8 = __attribute__((ext_vector_type(8))) short;
using f32x4  = __attribute__((ext_vector_type(4))) float;

__device__ __forceinline__ unsigned short f2bf(float f) {
  unsigned int u = __float_as_uint(f);
  u += 0x7FFF + ((u >> 16) & 1);
  return (unsigned short)(u >> 16);
}

__device__ __forceinline__ void async16(const unsigned short* g, unsigned short* l) {
  __builtin_amdgcn_global_load_lds((const __attribute__((address_space(1))) void*)g,
                                   (__attribute__((address_space(3))) void*)l,
                                   16, 0, 0);
}

#define BAR() __builtin_amdgcn_s_barrier()
#define WAIT_LGKM0() do { asm volatile("s_waitcnt lgkmcnt(0)" ::: "memory"); \
                          __builtin_amdgcn_sched_barrier(0); } while (0)
#define WAIT_VM(n) asm volatile("s_waitcnt vmcnt(" #n ")" ::: "memory")
#define MFMA16(a, b, c) __builtin_amdgcn_mfma_f32_16x16x32_bf16(a, b, c, 0, 0, 0)

// ---------------- weight transpose+convert: W[K,N] f32 -> Wt[N,K] bf16 ----------------
__global__ void wconv(const float* __restrict__ w0, const float* __restrict__ w1,
                      const float* __restrict__ w2, const float* __restrict__ w3,
                      unsigned short* __restrict__ Wt) {
  __shared__ unsigned short tile[64][65];
  const float* W = (blockIdx.z == 0) ? w0 : (blockIdx.z == 1) ? w1 : (blockIdx.z == 2) ? w2 : w3;
  unsigned short* O = Wt + (size_t)blockIdx.z * DIMS * DIMS;
  const int k0 = blockIdx.y * 64, n0 = blockIdx.x * 64;
  const int t = threadIdx.x;
  #pragma unroll
  for (int p = 0; p < 16; ++p) {
    int i = p * 4 + (t >> 6);
    int j = t & 63;
    tile[i][j] = f2bf(W[(size_t)(k0 + i) * DIMS + n0 + j]);
  }
  __syncthreads();
  #pragma unroll
  for (int p = 0; p < 16; ++p) {
    int a = p * 4 + (t >> 6);
    int b = t & 63;
    O[(size_t)(n0 + a) * DIMS + k0 + b] = tile[b][a];
  }
}

// ---------------- hidden f32 -> bf16 ----------------
__global__ void hconv(const float* __restrict__ in, unsigned short* __restrict__ outp) {
  const long n4 = (long)MROWS * DIMS / 4;
  long i = (long)blockIdx.x * blockDim.x + threadIdx.x;
  const long stride = (long)gridDim.x * blockDim.x;
  for (; i < n4; i += stride) {
    float4 v = ((const float4*)in)[i];
    ushort4 o;
    o.x = f2bf(v.x); o.y = f2bf(v.y); o.z = f2bf(v.z); o.w = f2bf(v.w);
    ((ushort4*)outp)[i] = o;
  }
}

// ---------------- RoPE table: [8192][64] cos/sin ----------------
__global__ void rope_tab(float* __restrict__ cosT, float* __restrict__ sinT) {
  int t = blockIdx.x * 256 + threadIdx.x;  // 524288 total
  int pos = t >> 6, i = t & 63;
  double inv = pow(10000.0, -(double)i / 64.0);
  double ang = (double)pos * inv;
  cosT[t] = (float)cos(ang);
  sinT[t] = (float)sin(ang);
}

// ---------------- 256x256 8-phase GEMM: A[M,K]bf16 @ Bt[N,K]^T ----------------
// 512 thr = 8 waves (2M x 4N), BK=64, LDS 128KB double-buffered.
// Single barrier per phase (end only): end-BAR + lgkm(0)-before-it guarantees all
// phase-N reads complete before any wave's phase-N+1 stage overwrites that region;
// P4/P8 vmcnt(6)+BAR publishes each staged tile before its consumers. Waves may
// de-phase by <=1 phase, overlapping one wave's ds_reads with the other's MFMAs.
// LDS swizzle: byte ^= (row&7)<<4 read-side; inverse-swizzled global source (rule 21).
// MODE 0: QKV, z-major mapping (FETCH-optimal, R3-measured 305MB); z<2 RoPE bf16 out;
//         z==2 writes V transposed to Vt[b,h,d,s]. MODE 1: O-proj (f32 out).
template<int MODE>
__global__ __launch_bounds__(512, 2) void gemm256(
    const unsigned short* __restrict__ A,
    const unsigned short* __restrict__ WtAll,
    unsigned short* __restrict__ OutB,
    float* __restrict__ OutF,
    const float* __restrict__ cosT,
    const float* __restrict__ sinT) {
  __shared__ __align__(1024) unsigned short lds[65536];  // 128 KiB
  unsigned short* const As0 = lds;           // buf0 A [256][64]
  unsigned short* const Bs0 = lds + 16384;   // buf0 B
  unsigned short* const As1 = lds + 32768;   // buf1 A
  unsigned short* const Bs1 = lds + 49152;   // buf1 B

  const int tid = threadIdx.x;
  const int wid = tid >> 6, lane = tid & 63;
  const int lo = lane & 15, hi = lane >> 4;
  const int wm = wid >> 2, wn = wid & 3;
  const int flip = (lo & 7) << 4;  // read-side XOR: byte ^= (row&7)<<4

  // T1: bijective XCD swizzle (grid % 8 == 0 for both modes)
  const int nwg = gridDim.x;
  const int orig = blockIdx.x;
  const int bid = (orig & 7) * (nwg >> 3) + (orig >> 3);

  // z-major mapping (R3): per XCD ~24 A-panels + one z's B matrix in L2
  int by, bx, z;
  if (MODE == 0) {
    z = bid >> 9;
    by = (bid & 511) >> 3;
    bx = bid & 7;
  } else {
    by = bid >> 3; bx = bid & 7; z = 3;
  }
  const int m0 = by * 256, n0 = bx * 256;
  const unsigned short* const Ag = A;
  const unsigned short* const Bg = WtAll + (size_t)z * DIMS * DIMS;

  f32x4 acc[8][4];
  #pragma unroll
  for (int i = 0; i < 8; ++i)
    #pragma unroll
    for (int j = 0; j < 4; ++j)
      acc[i][j] = (f32x4){0.f, 0.f, 0.f, 0.f};

  // stage one 128-row half-tile (16 KB): linear LDS dest, inverse-swizzled source.
  auto stage_half = [&](const unsigned short* __restrict__ G, int grow0, int tile,
                        unsigned short* dst) {
    const int k0 = tile * 64;
    #pragma unroll
    for (int h8 = 0; h8 < 2; ++h8) {
      const int c = h8 * 8 + wid;
      const int row = c * 8 + (lane >> 3);
      const int col8 = (lane & 7) ^ (lane >> 3);
      async16(G + (size_t)(grow0 + row) * DIMS + k0 + col8 * 8, dst + c * 512);
    }
  };
  auto rdA = [&](const unsigned short* base, int i, int kk) -> bf16x8 {
    const int r = i * 32 + wm * 16 + lo;
    const int cb = (kk * 64 + hi * 16) ^ flip;
    return *(const bf16x8*)((const char*)base + r * 128 + cb);
  };
  auto rdB = [&](const unsigned short* base, int j, int kk) -> bf16x8 {
    const int r = j * 64 + wn * 16 + lo;
    const int cb = (kk * 64 + hi * 16) ^ flip;
    return *(const bf16x8*)((const char*)base + r * 128 + cb);
  };

  bf16x8 aq[4][2], b0[2][2], b1[2][2];

  // prologue: tile0 full + {A0,B0,B1}(1); vmcnt(6) => tile0 landed, 3 halves in flight
  stage_half(Ag, m0,       0, As0);
  stage_half(Bg, n0,       0, Bs0);
  stage_half(Ag, m0 + 128, 0, As0 + 8192);
  stage_half(Bg, n0 + 128, 0, Bs0 + 8192);
  stage_half(Ag, m0,       1, As1);
  stage_half(Bg, n0,       1, Bs1);
  stage_half(Bg, n0 + 128, 1, Bs1 + 8192);
  WAIT_VM(6);
  BAR();

  #pragma unroll 1
  for (int it = 0; it < 16; ++it) {
    const int t = 2 * it;
    const bool pre = (it < 15);
    // ---- P1: read A0,B0(buf0); stage A1(t+1)->buf1; MFMA (qm0,qn0)
    #pragma unroll
    for (int i = 0; i < 4; ++i) { aq[i][0] = rdA(As0, i, 0); aq[i][1] = rdA(As0, i, 1); }
    #pragma unroll
    for (int j = 0; j < 2; ++j) { b0[j][0] = rdB(Bs0, j, 0); b0[j][1] = rdB(Bs0, j, 1); }
    stage_half(Ag, m0 + 128, t + 1, As1 + 8192);
    WAIT_LGKM0();
    __builtin_amdgcn_s_setprio(1);
    #pragma unroll
    for (int kk = 0; kk < 2; ++kk)
      #pragma unroll
      for (int i = 0; i < 4; ++i)
        #pragma unroll
        for (int j = 0; j < 2; ++j)
          acc[i][j] = MFMA16(aq[i][kk], b0[j][kk], acc[i][j]);
    __builtin_amdgcn_s_setprio(0);
    BAR();
    // ---- P2: read B1(buf0); stage A0(t+2)->buf0; MFMA (qm0,qn1)
    #pragma unroll
    for (int j = 0; j < 2; ++j) { b1[j][0] = rdB(Bs0, 2 + j, 0); b1[j][1] = rdB(Bs0, 2 + j, 1); }
    if (pre) stage_half(Ag, m0, t + 2, As0);
    WAIT_LGKM0();
    __builtin_amdgcn_s_setprio(1);
    #pragma unroll
    for (int kk = 0; kk < 2; ++kk)
      #pragma unroll
      for (int i = 0; i < 4; ++i)
        #pragma unroll
        for (int j = 0; j < 2; ++j)
          acc[i][2 + j] = MFMA16(aq[i][kk], b1[j][kk], acc[i][2 + j]);
    __builtin_amdgcn_s_setprio(0);
    BAR();
    // ---- P3: read A1(buf0) into aq; stage B0(t+2)->buf0; MFMA (qm1,qn0)
    #pragma unroll
    for (int i = 0; i < 4; ++i) { aq[i][0] = rdA(As0, 4 + i, 0); aq[i][1] = rdA(As0, 4 + i, 1); }
    if (pre) stage_half(Bg, n0, t + 2, Bs0);
    WAIT_LGKM0();
    __builtin_amdgcn_s_setprio(1);
    #pragma unroll
    for (int kk = 0; kk < 2; ++kk)
      #pragma unroll
      for (int i = 0; i < 4; ++i)
        #pragma unroll
        for (int j = 0; j < 2; ++j)
          acc[4 + i][j] = MFMA16(aq[i][kk], b0[j][kk], acc[4 + i][j]);
    __builtin_amdgcn_s_setprio(0);
    BAR();
    // ---- P4: stage B1(t+2)->buf0; MFMA (qm1,qn1); counted vmcnt
    if (pre) stage_half(Bg, n0 + 128, t + 2, Bs0 + 8192);
    __builtin_amdgcn_s_setprio(1);
    #pragma unroll
    for (int kk = 0; kk < 2; ++kk)
      #pragma unroll
      for (int i = 0; i < 4; ++i)
        #pragma unroll
        for (int j = 0; j < 2; ++j)
          acc[4 + i][2 + j] = MFMA16(aq[i][kk], b1[j][kk], acc[4 + i][2 + j]);
    __builtin_amdgcn_s_setprio(0);
    if (it == 15) { WAIT_VM(0); } else { WAIT_VM(6); }
    BAR();
    // ---- P5: read A0,B0(buf1); stage A1(t+2)->buf0; MFMA (qm0,qn0) of t+1
    #pragma unroll
    for (int i = 0; i < 4; ++i) { aq[i][0] = rdA(As1, i, 0); aq[i][1] = rdA(As1, i, 1); }
    #pragma unroll
    for (int j = 0; j < 2; ++j) { b0[j][0] = rdB(Bs1, j, 0); b0[j][1] = rdB(Bs1, j, 1); }
    if (pre) stage_half(Ag, m0 + 128, t + 2, As0 + 8192);
    WAIT_LGKM0();
    __builtin_amdgcn_s_setprio(1);
    #pragma unroll
    for (int kk = 0; kk < 2; ++kk)
      #pragma unroll
      for (int i = 0; i < 4; ++i)
        #pragma unroll
        for (int j = 0; j < 2; ++j)
          acc[i][j] = MFMA16(aq[i][kk], b0[j][kk], acc[i][j]);
    __builtin_amdgcn_s_setprio(0);
    BAR();
    // ---- P6: read B1(buf1); stage A0(t+3)->buf1; MFMA (qm0,qn1)
    #pragma unroll
    for (int j = 0; j < 2; ++j) { b1[j][0] = rdB(Bs1, 2 + j, 0); b1[j][1] = rdB(Bs1, 2 + j, 1); }
    if (pre) stage_half(Ag, m0, t + 3, As1);
    WAIT_LGKM0();
    __builtin_amdgcn_s_setprio(1);
    #pragma unroll
    for (int kk = 0; kk < 2; ++kk)
      #pragma unroll
      for (int i = 0; i < 4; ++i)
        #pragma unroll
        for (int j = 0; j < 2; ++j)
          acc[i][2 + j] = MFMA16(aq[i][kk], b1[j][kk], acc[i][2 + j]);
    __builtin_amdgcn_s_setprio(0);
    BAR();
    // ---- P7: read A1(buf1); stage B0(t+3)->buf1; MFMA (qm1,qn0)
    #pragma unroll
    for (int i = 0; i < 4; ++i) { aq[i][0] = rdA(As1, 4 + i, 0); aq[i][1] = rdA(As1, 4 + i, 1); }
    if (pre) stage_half(Bg, n0, t + 3, Bs1);
    WAIT_LGKM0();
    __builtin_amdgcn_s_setprio(1);
    #pragma unroll
    for (int kk = 0; kk < 2; ++kk)
      #pragma unroll
      for (int i = 0; i < 4; ++i)
        #pragma unroll
        for (int j = 0; j < 2; ++j)
          acc[4 + i][j] = MFMA16(aq[i][kk], b0[j][kk], acc[4 + i][j]);
    __builtin_amdgcn_s_setprio(0);
    BAR();
    // ---- P8: stage B1(t+3)->buf1; MFMA (qm1,qn1); counted vmcnt
    if (pre) stage_half(Bg, n0 + 128, t + 3, Bs1 + 8192);
    __builtin_amdgcn_s_setprio(1);
    #pragma unroll
    for (int kk = 0; kk < 2; ++kk)
      #pragma unroll
      for (int i = 0; i < 4; ++i)
        #pragma unroll
        for (int j = 0; j < 2; ++j)
          acc[4 + i][2 + j] = MFMA16(aq[i][kk], b1[j][kk], acc[4 + i][2 + j]);
    __builtin_amdgcn_s_setprio(0);
    WAIT_VM(6);
    BAR();
  }

  // epilogue
  if (MODE == 0 && z == 2) {
    // V transposed: Vt[b, h, d, s] with layout ((b*2048 + col) << 13) + s
    unsigned short* vt = OutB + (size_t)2 * MROWS * DIMS;
    #pragma unroll
    for (int i = 0; i < 8; ++i) {
      const int row0 = m0 + i * 32 + wm * 16 + hi * 4;
      const int bb = row0 >> 13;
      const int s0 = row0 & (SEQ - 1);
      #pragma unroll
      for (int j = 0; j < 4; ++j) {
        const int colg = n0 + j * 64 + wn * 16 + lo;
        ushort4 pk;
        pk.x = f2bf(acc[i][j][0]); pk.y = f2bf(acc[i][j][1]);
        pk.z = f2bf(acc[i][j][2]); pk.w = f2bf(acc[i][j][3]);
        *(ushort4*)&vt[(((size_t)(bb * 2048 + colg)) << 13) + s0] = pk;
      }
    }
  } else {
    unsigned short* outb = (MODE == 0) ? (OutB + (size_t)z * MROWS * DIMS)
                                       : (unsigned short*)nullptr;
    #pragma unroll
    for (int i = 0; i < 8; ++i) {
      #pragma unroll
      for (int rr = 0; rr < 4; ++rr) {
        const int row = m0 + i * 32 + wm * 16 + hi * 4 + rr;
        const int s = row & (SEQ - 1);
        if (MODE == 1) {
          float* o = OutF + (size_t)row * DIMS + n0;
          #pragma unroll
          for (int j = 0; j < 4; ++j) o[j * 64 + wn * 16 + lo] = acc[i][j][rr];
        } else {  // z < 2: RoPE
          unsigned short* o = outb + (size_t)row * DIMS + n0;
          const int d = wn * 16 + lo;  // < 64
          const float cc = cosT[s * 64 + d], sn = sinT[s * 64 + d];
          #pragma unroll
          for (int p = 0; p < 2; ++p) {
            const float v1 = acc[i][2 * p][rr], v2 = acc[i][2 * p + 1][rr];
            o[p * 128 + d]      = f2bf(v1 * cc - v2 * sn);
            o[p * 128 + d + 64] = f2bf(v2 * cc + v1 * sn);
          }
        }
      }
    }
  }
}

// ---------------- block sliding-window attention ----------------
// grid: B*C*H = 1024 blocks; block = 512 threads = 8 waves; wave = 32 q-rows.
// K staged [64 keys][128 d], V staged [128 d][64 keys] from pre-transposed Vt;
// both via global_load_lds, double-buffered (counted vmcnt), 16B-chunk XOR swizzle.
__global__ __launch_bounds__(512) void attn(
    const unsigned short* __restrict__ Qb,
    const unsigned short* __restrict__ Kb,
    const unsigned short* __restrict__ Vt,
    unsigned short* __restrict__ AO) {
  __shared__ unsigned short Ksm[2][64 * 128];
  __shared__ unsigned short Vsm[2][128 * 64];
  __shared__ unsigned short Psm[8 * 32 * 72];  // per wave [32 q][64 k + 8 pad]

  const int bid = blockIdx.x;
  const int h = bid & 15;
  const int c = (bid >> 4) & 31;
  const int b = bid >> 9;
  const int tid = threadIdx.x;
  const int wid = tid >> 6, lane = tid & 63;
  const int lo = lane & 15, hi = lane >> 4;
  const float SCALE = 0.08838834764831845f;  // 1/sqrt(128)

  // hoist Q fragments into registers
  bf16x8 qf[2][4];
  {
    const size_t base = ((size_t)(b * SEQ + c * WINW + wid * 32 + lo)) * DIMS + h * HD;
    #pragma unroll
    for (int m = 0; m < 2; ++m)
      #pragma unroll
      for (int ks = 0; ks < 4; ++ks)
        qf[m][ks] = *(const bf16x8*)&Qb[base + (size_t)m * 16 * DIMS + ks * 32 + hi * 8];
  }

  f32x4 O[2][8];
  float mrow[2][4], lrow[2][4];
  #pragma unroll
  for (int m = 0; m < 2; ++m) {
    #pragma unroll
    for (int n = 0; n < 8; ++n) O[m][n] = (f32x4){0.f, 0.f, 0.f, 0.f};
    #pragma unroll
    for (int r = 0; r < 4; ++r) { mrow[m][r] = -INFINITY; lrow[m][r] = 0.f; }
  }

  unsigned short* Pw = Psm + wid * 32 * 72;
  const int t0 = (c == 0) ? 4 : 0;  // block-uniform: chunk 0 has no previous chunk

  const unsigned short* Kg0 = Kb + ((size_t)(b * SEQ + (c - 1) * WINW)) * DIMS + h * HD;
  const unsigned short* Vg0 = Vt + (((size_t)(b * 2048 + h * HD)) << 13) + (c - 1) * WINW;

  auto stageKV = [&](int t, int pb) {
    #pragma unroll
    for (int p = 0; p < 2; ++p) {  // K: 64 rows x 16 chunks of 16B
      const int cid = p * 512 + tid;
      const int row = cid >> 4, c16 = cid & 15;
      async16(Kg0 + (size_t)(t * 64 + row) * DIMS + ((c16 ^ (row & 7)) << 3),
              &Ksm[pb][cid * 8]);
    }
    #pragma unroll
    for (int p = 0; p < 2; ++p) {  // V^T: 128 d-rows x 8 chunks of 16B
      const int cid = p * 512 + tid;
      const int rd = cid >> 3, c8 = cid & 7;
      async16(Vg0 + ((size_t)rd << 13) + t * 64 + ((c8 ^ (rd & 7)) << 3),
              &Vsm[pb][cid * 8]);
    }
  };

  stageKV(t0, t0 & 1);
  for (int t = t0; t < 8; ++t) {
    const int pb = t & 1;
    if (t < 7) { stageKV(t + 1, pb ^ 1); WAIT_VM(4); } else { WAIT_VM(0); }
    BAR();

    // S = Q @ K^T  (64 keys)
    f32x4 S[2][4];
    #pragma unroll
    for (int m = 0; m < 2; ++m)
      #pragma unroll
      for (int n = 0; n < 4; ++n)
        S[m][n] = (f32x4){0.f, 0.f, 0.f, 0.f};
    const char* Kbase = (const char*)&Ksm[pb][0];
    #pragma unroll
    for (int ks = 0; ks < 4; ++ks) {
      bf16x8 kf[4];
      #pragma unroll
      for (int n = 0; n < 4; ++n)
        kf[n] = *(const bf16x8*)(Kbase + (n * 16 + lo) * 256 +
                                 (((ks * 4 + hi) ^ (lo & 7)) << 4));
      #pragma unroll
      for (int m = 0; m < 2; ++m)
        #pragma unroll
        for (int n = 0; n < 4; ++n)
          S[m][n] = MFMA16(qf[m][ks], kf[n], S[m][n]);
    }

    // mask + per-row tile max
    float tmax[2][4];
    #pragma unroll
    for (int m = 0; m < 2; ++m) {
      #pragma unroll
      for (int r = 0; r < 4; ++r) {
        const int qrow = wid * 32 + m * 16 + hi * 4 + r;
        float tm = -INFINITY;
        #pragma unroll
        for (int n = 0; n < 4; ++n) {
          const int kc = t * 64 + n * 16 + lo;
          float v = S[m][n][r] * SCALE;
          const bool ok = (kc < WINW) ? (c > 0) : ((kc - WINW) <= qrow);
          v = ok ? v : -INFINITY;
          S[m][n][r] = v;
          tm = fmaxf(tm, v);
        }
        tm = fmaxf(tm, __shfl_xor(tm, 1));
        tm = fmaxf(tm, __shfl_xor(tm, 2));
        tm = fmaxf(tm, __shfl_xor(tm, 4));
        tm = fmaxf(tm, __shfl_xor(tm, 8));
        tmax[m][r] = tm;
      }
    }
    // T13 defer-max: skip rescale when all rows drift <= 8
    float need = -INFINITY;
    #pragma unroll
    for (int m = 0; m < 2; ++m)
      #pragma unroll
      for (int r = 0; r < 4; ++r)
        need = fmaxf(need, tmax[m][r] - mrow[m][r]);
    const bool fast = __all(need <= 8.0f);

    #pragma unroll
    for (int m = 0; m < 2; ++m) {
      #pragma unroll
      for (int r = 0; r < 4; ++r) {
        float mused = mrow[m][r];
        if (!fast) {
          mused = fmaxf(mused, tmax[m][r]);
          const float corr = __expf(mrow[m][r] - mused);
          lrow[m][r] *= corr;
          #pragma unroll
          for (int n = 0; n < 8; ++n) O[m][n][r] *= corr;
          mrow[m][r] = mused;
        }
        float rsum = 0.f;
        #pragma unroll
        for (int n = 0; n < 4; ++n) {
          const float p = __expf(S[m][n][r] - mused);
          S[m][n][r] = p;
          rsum += p;
        }
        rsum += __shfl_xor(rsum, 1);
        rsum += __shfl_xor(rsum, 2);
        rsum += __shfl_xor(rsum, 4);
        rsum += __shfl_xor(rsum, 8);
        lrow[m][r] += rsum;
        #pragma unroll
        for (int n = 0; n < 4; ++n)
          Pw[(m * 16 + hi * 4 + r) * 72 + n * 16 + lo] = f2bf(S[m][n][r]);
      }
    }
    asm volatile("" ::: "memory");  // keep P stores before P reads (DS in-order per wave)

    // O += P @ V
    const char* Vbase = (const char*)&Vsm[pb][0];
    #pragma unroll
    for (int kk = 0; kk < 2; ++kk) {
      const int ko = kk * 32 + hi * 8;
      bf16x8 pf[2], vf[8];
      #pragma unroll
      for (int m = 0; m < 2; ++m)
        pf[m] = *(const bf16x8*)&Pw[(m * 16 + lo) * 72 + ko];
      #pragma unroll
      for (int n = 0; n < 8; ++n)
        vf[n] = *(const bf16x8*)(Vbase + (n * 16 + lo) * 128 +
                                 (((kk * 4 + hi) ^ (lo & 7)) << 4));
      #pragma unroll
      for (int m = 0; m < 2; ++m)
        #pragma unroll
        for (int n = 0; n < 8; ++n)
          O[m][n] = MFMA16(pf[m], vf[n], O[m][n]);
    }
    BAR();
  }

  // normalize + write bf16 attention output [B,S,H*D]
  #pragma unroll
  for (int m = 0; m < 2; ++m) {
    #pragma unroll
    for (int r = 0; r < 4; ++r) {
      const float inv = 1.f / lrow[m][r];
      const size_t row = (size_t)(b * SEQ + c * WINW + wid * 32 + m * 16 + hi * 4 + r);
      unsigned short* o = AO + row * DIMS + h * HD;
      #pragma unroll
      for (int n = 0; n < 8; ++n)
        o[n * 16 + lo] = f2bf(O[m][n][r] * inv);
    }
  }
}

extern "C" void kernel_launch(void* const* d_in, const int* in_sizes, int n_in,
                              void* d_out, int out_size, void* d_ws, size_t ws_size,
                              hipStream_t stream) {
  const float* H  = (const float*)d_in[0];
  const float* Wq = (const float*)d_in[1];
  const float* Wk = (const float*)d_in[2];
  const float* Wv = (const float*)d_in[3];
  const float* Wo = (const float*)d_in[4];
  float* out = (float*)d_out;

  // workspace layout (373.3 MB total)
  unsigned short* Wt  = (unsigned short*)d_ws;                  // 4*2048*2048 bf16
  unsigned short* Hb  = Wt + (size_t)4 * DIMS * DIMS;           // 16384*2048 bf16
  unsigned short* QKV = Hb + (size_t)MROWS * DIMS;              // 3 x 16384*2048 bf16 (z=2 = Vt)
  unsigned short* AO  = QKV + (size_t)3 * MROWS * DIMS;         // 16384*2048 bf16
  float* cosT = (float*)(AO + (size_t)MROWS * DIMS);            // 8192*64 f32
  float* sinT = cosT + (size_t)SEQ * 64;

  wconv<<<dim3(32, 32, 4), 256, 0, stream>>>(Wq, Wk, Wv, Wo, Wt);
  hconv<<<2048, 256, 0, stream>>>(H, Hb);
  rope_tab<<<2048, 256, 0, stream>>>(cosT, sinT);
  gemm256<0><<<1536, 512, 0, stream>>>(Hb, Wt, QKV, nullptr, cosT, sinT);
  attn<<<dim3(1024), 512, 0, stream>>>(QKV, QKV + (size_t)MROWS * DIMS,
                                       QKV + (size_t)2 * MROWS * DIMS, AO);
  gemm256<1><<<512, 512, 0, stream>>>(AO, Wt, nullptr, out, cosT, sinT);
}